// Round 6
// baseline (164.921 us; speedup 1.0000x reference)
//
#include <hip/hip_runtime.h>
#include <stdint.h>

// MAB block: B=32, N=512, D=512, H=8, dh=64.  M = B*N = 16384.
#define SCALE_ 0.044194173824159216f

typedef __attribute__((ext_vector_type(8))) short bf16x8;
typedef __attribute__((ext_vector_type(4))) float f32x4;

__device__ __forceinline__ ushort f2b(float f) {
  union { float f; uint32_t u; } v; v.f = f;
  return (ushort)((v.u + 0x7fffu + ((v.u >> 16) & 1u)) >> 16);  // RNE
}
__device__ __forceinline__ uint32_t cvtpk(float lo, float hi) {
  uint32_t r; asm("v_cvt_pk_bf16_f32 %0, %1, %2" : "=v"(r) : "v"(lo), "v"(hi)); return r;
}
__device__ __forceinline__ void gld16(void* lds, const void* g) {
  __builtin_amdgcn_global_load_lds(
      (const __attribute__((address_space(1))) uint32_t*)g,
      (__attribute__((address_space(3))) uint32_t*)lds, 16, 0, 0);
}

// ---------------- fp32 -> bf16 convert (Q, K, 6 weights) ----------------
__global__ __launch_bounds__(256)
void k_cvt(const float* __restrict__ Q, const float* __restrict__ K,
           const float* __restrict__ w0, const float* __restrict__ w1,
           const float* __restrict__ w2, const float* __restrict__ w3,
           const float* __restrict__ w4, const float* __restrict__ w5,
           ushort* __restrict__ Qb, ushort* __restrict__ Kb, ushort* __restrict__ Wb)
{
  const long long NQ = 8388608LL, NW = 262144LL;
  long long i = ((long long)blockIdx.x * 256 + threadIdx.x) * 4;
  const float* src; ushort* dst; long long off;
  if (i < NQ)        { src = Q; dst = Qb; off = i; }
  else if (i < 2*NQ) { src = K; dst = Kb; off = i - NQ; }
  else {
    long long j = i - 2*NQ; int seg = (int)(j / NW); off = j - (long long)seg * NW;
    switch (seg) { case 0: src = w0; break; case 1: src = w1; break; case 2: src = w2; break;
                   case 3: src = w3; break; case 4: src = w4; break; default: src = w5; }
    dst = Wb + (size_t)seg * NW;
  }
  float4 v = *(const float4*)(src + off);
  ushort4 o = make_ushort4(f2b(v.x), f2b(v.y), f2b(v.z), f2b(v.w));
  *(ushort4*)(dst + off) = o;
}

// ---------------- GEMM C = A(bf16,[M,512]) @ Bw(bf16,[512,512])^T ----------------
// 256x128 tile, BK=64, 512 threads (8 waves = 4M x 2N, per-wave 64x64).
// Triple-buffered LDS (3 x 48KB), counted vmcnt(6), PHASE-SPLIT K-step (m201 style):
//   R1 {ds_read ks0 | stage-A} -> bar -> R2 {MFMA ks0 | ds_read ks1 | stage-B} -> bar
//   -> R3 {MFMA ks1} -> next iter {vmcnt(6); bar}.
// 3-bit slot swizzle: byte ^= (row&7)<<4 (inverse-swizzled source, linear dest, XOR'd reads).
// EPI: 0 = bias->bf16  1 = Q + (acc+bias) -> f32 + bf16  2 = relu->bf16
//      3 = out += acc+bias  4 = v-projection: write transposed vpT[(b,h,d),k]
template<int EPI>
__device__ __forceinline__ void gemm_body(const ushort* __restrict__ A, const ushort* __restrict__ Bw,
                                          const float* __restrict__ bias, const float* __restrict__ extra,
                                          float* __restrict__ outf, ushort* __restrict__ outb,
                                          char* lds, int m0, int n0)
{
  const int t = threadIdx.x;           // 0..511
  const int w = t >> 6, lane = t & 63;
  const int wm = w >> 1, wn = w & 1;   // 4M x 2N wave grid
  const int rA = lane & 15, g = lane >> 4;

  // staging: per K-tile 48KB: A [0,32768) = 256 rows x 128B, B [32768,49152) = 128 x 128B.
  // Inverse-swizzle source: U = L ^ (((L>>7)&7)<<4)  (involution; bits 4-6 sub-row).
  const ushort* srcA[4]; int ldsA[4];
#pragma unroll
  for (int j = 0; j < 4; j++) {
    int L = (t + j*512) * 16;
    int U = L ^ (((L >> 7) & 7) << 4);
    srcA[j] = A + (size_t)(m0 + (U >> 7))*512 + ((U & 127) >> 1);
    ldsA[j] = L;
  }
  const ushort* srcB[2]; int ldsB[2];
#pragma unroll
  for (int j = 0; j < 2; j++) {
    int L = (t + j*512) * 16;
    int U = L ^ (((L >> 7) & 7) << 4);
    srcB[j] = Bw + (size_t)(n0 + (U >> 7))*512 + ((U & 127) >> 1);
    ldsB[j] = 32768 + L;
  }

#define STAGE_A(ti) do { char* bb_ = lds + ((ti) % 3) * 49152; \
    _Pragma("unroll") \
    for (int j = 0; j < 4; j++) gld16(bb_ + ldsA[j], srcA[j] + (ti)*64); } while (0)
#define STAGE_B(ti) do { char* bb_ = lds + ((ti) % 3) * 49152; \
    _Pragma("unroll") \
    for (int j = 0; j < 2; j++) gld16(bb_ + ldsB[j], srcB[j] + (ti)*64); } while (0)

  STAGE_A(0); STAGE_B(0);
  STAGE_A(1); STAGE_B(1);

  f32x4 acc[4][4] = {};
  for (int i = 0; i < 8; i++) {
    // ---- tile-i readiness: oldest 6 loads (tile i) landed; tile i+1's 6 in flight ----
    if (i < 7) asm volatile("s_waitcnt vmcnt(6)" ::: "memory");
    else       asm volatile("s_waitcnt vmcnt(0)" ::: "memory");
    __builtin_amdgcn_s_barrier();
    __builtin_amdgcn_sched_barrier(0);
    const char* bufc = lds + (i % 3) * 49152;

    // ---- R1: ds_read ks=0 fragments; issue stage-A(i+2) ----
    bf16x8 afA[4], bfA[4];
#pragma unroll
    for (int m = 0; m < 4; m++) {
      int row = wm*64 + m*16 + rA;
      afA[m] = *(const bf16x8*)(bufc + ((row*128 + g*16) ^ ((row & 7) << 4)));
    }
#pragma unroll
    for (int n = 0; n < 4; n++) {
      int row = wn*64 + n*16 + rA;
      bfA[n] = *(const bf16x8*)(bufc + 32768 + ((row*128 + g*16) ^ ((row & 7) << 4)));
    }
    if (i < 6) STAGE_A(i + 2);
    __builtin_amdgcn_s_barrier();
    __builtin_amdgcn_sched_barrier(0);

    // ---- R2: MFMA ks=0 cluster  ||  ds_read ks=1  ||  stage-B(i+2) ----
    bf16x8 afB[4], bfB[4];
#pragma unroll
    for (int m = 0; m < 4; m++) {
      int row = wm*64 + m*16 + rA;
      afB[m] = *(const bf16x8*)(bufc + ((row*128 + 64 + g*16) ^ ((row & 7) << 4)));
    }
#pragma unroll
    for (int n = 0; n < 4; n++) {
      int row = wn*64 + n*16 + rA;
      bfB[n] = *(const bf16x8*)(bufc + 32768 + ((row*128 + 64 + g*16) ^ ((row & 7) << 4)));
    }
    if (i < 6) STAGE_B(i + 2);
    __builtin_amdgcn_s_setprio(1);
#pragma unroll
    for (int m = 0; m < 4; m++)
#pragma unroll
      for (int n = 0; n < 4; n++)
        acc[m][n] = __builtin_amdgcn_mfma_f32_16x16x32_bf16(afA[m], bfA[n], acc[m][n], 0, 0, 0);
    __builtin_amdgcn_s_setprio(0);
    __builtin_amdgcn_s_barrier();
    __builtin_amdgcn_sched_barrier(0);

    // ---- R3: MFMA ks=1 cluster ----
    __builtin_amdgcn_s_setprio(1);
#pragma unroll
    for (int m = 0; m < 4; m++)
#pragma unroll
      for (int n = 0; n < 4; n++)
        acc[m][n] = __builtin_amdgcn_mfma_f32_16x16x32_bf16(afB[m], bfB[n], acc[m][n], 0, 0, 0);
    __builtin_amdgcn_s_setprio(0);
  }
#undef STAGE_A
#undef STAGE_B

#pragma unroll
  for (int m = 0; m < 4; m++)
#pragma unroll
    for (int n = 0; n < 4; n++) {
      int col = n0 + wn*64 + n*16 + rA;
      float bb = bias[col];
      if (EPI == 4) {
        // transposed write: C[row=k, col=h*64+d] -> vpT[(b*8+h)*64+d][k], 4 k packed
        int b = m0 >> 9, k0 = m0 & 511;
        int hh = col >> 6, dl = col & 63;
        int kg = k0 + wm*64 + m*16 + g*4;
        float v0 = acc[m][n][0] + bb, v1 = acc[m][n][1] + bb;
        float v2 = acc[m][n][2] + bb, v3 = acc[m][n][3] + bb;
        uint2 pk;
        pk.x = (uint32_t)f2b(v0) | ((uint32_t)f2b(v1) << 16);
        pk.y = (uint32_t)f2b(v2) | ((uint32_t)f2b(v3) << 16);
        *(uint2*)(outb + ((size_t)((b*8 + hh)*64 + dl)*512 + kg)) = pk;
      } else {
#pragma unroll
        for (int r = 0; r < 4; r++) {
          int row = m0 + wm*64 + m*16 + g*4 + r;
          size_t idx = (size_t)row*512 + col;
          float v = acc[m][n][r] + bb;
          if (EPI == 0)      outb[idx] = f2b(v);
          else if (EPI == 1) { float o = extra[idx] + v; outf[idx] = o; outb[idx] = f2b(o); }
          else if (EPI == 2) outb[idx] = f2b(v > 0.f ? v : 0.f);
          else               outf[idx] += v;
        }
      }
    }
}

template<int EPI>
__global__ __launch_bounds__(512, 2)
void k_gemm(const ushort* __restrict__ A, const ushort* __restrict__ Bw,
            const float* __restrict__ bias, const float* __restrict__ extra,
            float* __restrict__ outf, ushort* __restrict__ outb)
{
  __shared__ __align__(16) char lds[3*49152];   // 144 KB
  gemm_body<EPI>(A, Bw, bias, extra, outf, outb, lds, blockIdx.x*256, blockIdx.y*128);
}

// fused qkv projection; z=2 (v) writes transposed vpT directly
__global__ __launch_bounds__(512, 2)
void k_gemm_qkv(const ushort* __restrict__ Qb, const ushort* __restrict__ Kb,
                const ushort* __restrict__ Wb, const float* __restrict__ bq,
                const float* __restrict__ bk, const float* __restrict__ bvv,
                ushort* __restrict__ qkout, ushort* __restrict__ vpT)
{
  __shared__ __align__(16) char lds[3*49152];
  int z = blockIdx.z;
  if (z == 2) {
    gemm_body<4>(Kb, Wb + 2*(size_t)262144, bvv, nullptr, nullptr,
                 vpT, lds, blockIdx.x*256, blockIdx.y*128);
  } else {
    const ushort* A = (z == 0) ? Qb : Kb;
    const float* bias = (z == 0) ? bq : bk;
    gemm_body<0>(A, Wb + (size_t)z*262144, bias, nullptr, nullptr,
                 qkout + (size_t)z*8388608, lds, blockIdx.x*256, blockIdx.y*128);
  }
}

// ---------------- K2: zinv[bh,k] = 1/sum_q exp(s*scale) ----------------
__global__ __launch_bounds__(256, 2)
void k_z(const ushort* __restrict__ qp, const ushort* __restrict__ kp, float* __restrict__ zinv)
{
  __shared__ __align__(16) ushort qt[2*8192];   // 2 x [128 q][64 d] (swizzled), 32KB
  int bid = blockIdx.x;
  int bh = bid >> 1, kh = bid & 1;
  int b = bh >> 3, h = bh & 7;
  int t = threadIdx.x, w = t >> 6, lane = t & 63;
  int rA = lane & 15, g = lane >> 4;
  const ushort* qbase = qp + (size_t)(b*512)*512 + h*64;
  bf16x8 kf[4][2];
#pragma unroll
  for (int n = 0; n < 4; n++)
#pragma unroll
    for (int ks = 0; ks < 2; ks++)
      kf[n][ks] = *(const bf16x8*)(kp + (size_t)(b*512 + kh*256 + w*64 + n*16 + rA)*512 + h*64 + ks*32 + g*8);

#define Z_STAGE(buf, qb) do { \
    _Pragma("unroll") \
    for (int i = 0; i < 4; i++) { \
      int c = i*256 + w*64 + lane; \
      int row = c >> 3, sl = c & 7; \
      gld16((char*)qt + (buf)*16384 + i*4096 + w*1024, \
            qbase + (size_t)((qb)*128 + row)*512 + ((sl ^ (row & 7))*8)); } } while (0)

  Z_STAGE(0, 0);
  __syncthreads();
  float Zacc[4] = {0.f, 0.f, 0.f, 0.f};
  for (int qb = 0; qb < 4; qb++) {
    const int cur = qb & 1;
    if (qb < 3) Z_STAGE(cur ^ 1, qb + 1);
    const ushort* qtb = qt + cur*8192;
    f32x4 acc[8][4] = {};
#pragma unroll
    for (int ks = 0; ks < 2; ks++) {
      bf16x8 af[8];
#pragma unroll
      for (int m = 0; m < 8; m++) {
        int q = m*16 + rA;
        af[m] = *(const bf16x8*)(qtb + q*64 + (((ks*4 + g) ^ (q & 7))*8));
      }
      __builtin_amdgcn_s_setprio(1);
#pragma unroll
      for (int m = 0; m < 8; m++)
#pragma unroll
        for (int n = 0; n < 4; n++)
          acc[m][n] = __builtin_amdgcn_mfma_f32_16x16x32_bf16(af[m], kf[n][ks], acc[m][n], 0, 0, 0);
      __builtin_amdgcn_s_setprio(0);
    }
#pragma unroll
    for (int m = 0; m < 8; m++)
#pragma unroll
      for (int n = 0; n < 4; n++) {
        float s = 0.f;
#pragma unroll
        for (int r = 0; r < 4; r++) s += __expf(acc[m][n][r] * SCALE_);
        Zacc[n] += s;
      }
    __syncthreads();
  }
#undef Z_STAGE
#pragma unroll
  for (int n = 0; n < 4; n++) {
    float v = Zacc[n];
    v += __shfl_xor(v, 16);
    v += __shfl_xor(v, 32);
    if (lane < 16) zinv[(size_t)bh*512 + kh*256 + w*64 + n*16 + lane] = 1.0f / v;
  }
}

// ---------------- K3: attn = (exp(QK^T*scale)*zinv) @ V ----------------
__global__ __launch_bounds__(256, 2)
void k_attn(const ushort* __restrict__ qp, const ushort* __restrict__ kp,
            const ushort* __restrict__ vpT, const float* __restrict__ zinv,
            ushort* __restrict__ attn)
{
  __shared__ __align__(16) ushort kt2[2*4096];  // 2 x [64 k][64 d] swizzled, 16KB
  __shared__ __align__(16) ushort vt2[2*4096];  // 2 x [64 d][64 k] swizzled, 16KB
  __shared__ __align__(16) ushort P[4*4096];    // per-wave [64 q][64 k] swizzled, 32KB
  __shared__ float zl[512];
  int bid = blockIdx.x;
  int bh = bid >> 1, qh = bid & 1;
  int b = bh >> 3, h = bh & 7;
  int t = threadIdx.x, w = t >> 6, lane = t & 63;
  int rA = lane & 15, g = lane >> 4;
  const ushort* kbase = kp + (size_t)(b*512)*512 + h*64;
  const ushort* vbase = vpT + (size_t)bh*64*512;
  ushort* Pw = P + w*4096;
  bf16x8 qf[4][2];
#pragma unroll
  for (int m = 0; m < 4; m++)
#pragma unroll
    for (int ks = 0; ks < 2; ks++)
      qf[m][ks] = *(const bf16x8*)(qp + (size_t)(b*512 + qh*256 + w*64 + m*16 + rA)*512 + h*64 + ks*32 + g*8);

#define A_STAGE(buf, kc) do { \
    _Pragma("unroll") \
    for (int i = 0; i < 2; i++) { \
      int c = i*256 + w*64 + lane; \
      { int k = c >> 3, sl = c & 7; \
        gld16((char*)kt2 + (buf)*8192 + i*4096 + w*1024, \
              kbase + (size_t)((kc)*64 + k)*512 + ((sl ^ (k & 7))*8)); } \
      { int d = c >> 3, sl = c & 7; \
        gld16((char*)vt2 + (buf)*8192 + i*4096 + w*1024, \
              vbase + (size_t)d*512 + (kc)*64 + ((sl ^ (d & 7))*8)); } } } while (0)

  A_STAGE(0, 0);
  zl[t]       = zinv[(size_t)bh*512 + t];
  zl[t + 256] = zinv[(size_t)bh*512 + t + 256];
  __syncthreads();
  f32x4 oacc[4][4] = {};
  for (int kc = 0; kc < 8; kc++) {
    const int cur = kc & 1;
    if (kc < 7) A_STAGE(cur ^ 1, kc + 1);
    const ushort* ktb = kt2 + cur*4096;
    const ushort* vtb = vt2 + cur*4096;
#pragma unroll
    for (int knh = 0; knh < 2; knh++) {
      f32x4 sacc[2][4] = {};
#pragma unroll
      for (int ks = 0; ks < 2; ks++) {
        bf16x8 kfr[2];
#pragma unroll
        for (int kn2 = 0; kn2 < 2; kn2++) {
          int k = (knh*2 + kn2)*16 + rA;
          kfr[kn2] = *(const bf16x8*)(ktb + k*64 + (((ks*4 + g) ^ (k & 7))*8));
        }
        __builtin_amdgcn_s_setprio(1);
#pragma unroll
        for (int kn2 = 0; kn2 < 2; kn2++)
#pragma unroll
          for (int m = 0; m < 4; m++)
            sacc[kn2][m] = __builtin_amdgcn_mfma_f32_16x16x32_bf16(kfr[kn2], qf[m][ks], sacc[kn2][m], 0, 0, 0);
        __builtin_amdgcn_s_setprio(0);
      }
#pragma unroll
      for (int kn2 = 0; kn2 < 2; kn2++) {
        int kn = knh*2 + kn2;
        f32x4 zv = *(const f32x4*)&zl[kc*64 + kn*16 + g*4];
#pragma unroll
        for (int m = 0; m < 4; m++) {
          float e0 = __expf(sacc[kn2][m][0] * SCALE_) * zv[0];
          float e1 = __expf(sacc[kn2][m][1] * SCALE_) * zv[1];
          float e2 = __expf(sacc[kn2][m][2] * SCALE_) * zv[2];
          float e3 = __expf(sacc[kn2][m][3] * SCALE_) * zv[3];
          uint2 pk; pk.x = cvtpk(e0, e1); pk.y = cvtpk(e2, e3);
          int q = m*16 + rA;
          int kb2 = kn*32 + g*8;
          *(uint2*)((char*)Pw + q*128 + (kb2 ^ ((q & 7) << 4))) = pk;
        }
      }
    }
#pragma unroll
    for (int ks = 0; ks < 2; ks++) {
      bf16x8 pa[4], vb[4];
#pragma unroll
      for (int m = 0; m < 4; m++) {
        int q = m*16 + rA;
        pa[m] = *(const bf16x8*)((const char*)Pw + q*128 + ((ks*64 + g*16) ^ ((q & 7) << 4)));
      }
#pragma unroll
      for (int n = 0; n < 4; n++) {
        int d = n*16 + rA;
        vb[n] = *(const bf16x8*)((const char*)vtb + d*128 + ((ks*64 + g*16) ^ ((d & 7) << 4)));
      }
      __builtin_amdgcn_s_setprio(1);
#pragma unroll
      for (int m = 0; m < 4; m++)
#pragma unroll
        for (int n = 0; n < 4; n++)
          oacc[m][n] = __builtin_amdgcn_mfma_f32_16x16x32_bf16(pa[m], vb[n], oacc[m][n], 0, 0, 0);
      __builtin_amdgcn_s_setprio(0);
    }
    __syncthreads();
  }
#undef A_STAGE
#pragma unroll
  for (int m = 0; m < 4; m++)
#pragma unroll
    for (int n = 0; n < 4; n++)
#pragma unroll
      for (int r = 0; r < 4; r++) {
        int q = qh*256 + w*64 + m*16 + g*4 + r;
        int dcol = h*64 + n*16 + rA;
        attn[(size_t)(b*512 + q)*512 + dcol] = f2b(oacc[m][n][r]);
      }
}

// ---------------- host launcher ----------------
extern "C" void kernel_launch(void* const* d_in, const int* in_sizes, int n_in,
                              void* d_out, int out_size, void* d_ws, size_t ws_size,
                              hipStream_t stream) {
  const float* Q  = (const float*)d_in[0];
  const float* K  = (const float*)d_in[1];
  const float* Wq = (const float*)d_in[2];
  const float* bq = (const float*)d_in[3];
  const float* Wk = (const float*)d_in[4];
  const float* bk = (const float*)d_in[5];
  const float* Wv = (const float*)d_in[6];
  const float* bv = (const float*)d_in[7];
  const float* Wo = (const float*)d_in[8];
  const float* bo = (const float*)d_in[9];
  const float* W1 = (const float*)d_in[10];
  const float* b1 = (const float*)d_in[11];
  const float* W2 = (const float*)d_in[12];
  const float* b2 = (const float*)d_in[13];
  float* out = (float*)d_out;

  const size_t SZ = (size_t)16384 * 512;
  ushort* Qb   = (ushort*)d_ws;                 // later reused as attn
  ushort* Kb   = Qb + SZ;                       // later reused as outb
  ushort* qp   = Kb + SZ;
  ushort* kp   = qp + SZ;
  ushort* vpT  = kp + SZ;                       // v-projection, transposed; later reused as h1
  ushort* Wb   = vpT + SZ;
  float*  zinv = (float*)(Wb + 6 * (size_t)262144);
  ushort* attn = Qb;
  ushort* outb = Kb;
  ushort* h1   = vpT;

  k_cvt<<<dim3(17920), dim3(256), 0, stream>>>(Q, K, Wq, Wk, Wv, Wo, W1, W2, Qb, Kb, Wb);
  k_gemm_qkv<<<dim3(64, 4, 3), dim3(512), 0, stream>>>(Qb, Kb, Wb, bq, bk, bv, qp, vpT);
  k_z<<<dim3(512), dim3(256), 0, stream>>>(qp, kp, zinv);
  k_attn<<<dim3(512), dim3(256), 0, stream>>>(qp, kp, vpT, zinv, attn);
  k_gemm<1><<<dim3(64, 4), dim3(512), 0, stream>>>(attn, Wb + 3*(size_t)262144, bo, Q, out, outb);
  k_gemm<2><<<dim3(64, 4), dim3(512), 0, stream>>>(outb, Wb + 4*(size_t)262144, b1, nullptr, nullptr, h1);
  k_gemm<3><<<dim3(64, 4), dim3(512), 0, stream>>>(h1, Wb + 5*(size_t)262144, b2, nullptr, out, nullptr);
}

// Round 7
// 156.607 us; speedup vs baseline: 1.0531x; 1.0531x over previous
//
#include <hip/hip_runtime.h>
#include <stdint.h>

// MAB block: B=32, N=512, D=512, H=8, dh=64.  M = B*N = 16384.
#define SCALE_ 0.044194173824159216f

typedef __attribute__((ext_vector_type(8))) short bf16x8;
typedef __attribute__((ext_vector_type(4))) float f32x4;

__device__ __forceinline__ ushort f2b(float f) {
  union { float f; uint32_t u; } v; v.f = f;
  return (ushort)((v.u + 0x7fffu + ((v.u >> 16) & 1u)) >> 16);  // RNE
}
__device__ __forceinline__ uint32_t cvtpk(float lo, float hi) {
  uint32_t r; asm("v_cvt_pk_bf16_f32 %0, %1, %2" : "=v"(r) : "v"(lo), "v"(hi)); return r;
}
__device__ __forceinline__ void gld16(void* lds, const void* g) {
  __builtin_amdgcn_global_load_lds(
      (const __attribute__((address_space(1))) uint32_t*)g,
      (__attribute__((address_space(3))) uint32_t*)lds, 16, 0, 0);
}

// ---------------- fp32 -> bf16 convert (Q, K, 6 weights) ----------------
__global__ __launch_bounds__(256)
void k_cvt(const float* __restrict__ Q, const float* __restrict__ K,
           const float* __restrict__ w0, const float* __restrict__ w1,
           const float* __restrict__ w2, const float* __restrict__ w3,
           const float* __restrict__ w4, const float* __restrict__ w5,
           ushort* __restrict__ Qb, ushort* __restrict__ Kb, ushort* __restrict__ Wb)
{
  const long long NQ = 8388608LL, NW = 262144LL;
  long long i = ((long long)blockIdx.x * 256 + threadIdx.x) * 4;
  const float* src; ushort* dst; long long off;
  if (i < NQ)        { src = Q; dst = Qb; off = i; }
  else if (i < 2*NQ) { src = K; dst = Kb; off = i - NQ; }
  else {
    long long j = i - 2*NQ; int seg = (int)(j / NW); off = j - (long long)seg * NW;
    switch (seg) { case 0: src = w0; break; case 1: src = w1; break; case 2: src = w2; break;
                   case 3: src = w3; break; case 4: src = w4; break; default: src = w5; }
    dst = Wb + (size_t)seg * NW;
  }
  float4 v = *(const float4*)(src + off);
  ushort4 o = make_ushort4(f2b(v.x), f2b(v.y), f2b(v.z), f2b(v.w));
  *(ushort4*)(dst + off) = o;
}

// ---------------- GEMM C = A(bf16,[M,512]) @ Bw(bf16,[512,512])^T ----------------
// 256x128 tile, BK=64, 512 threads (8 waves = 4M x 2N).  Triple-buffered LDS,
// counted vmcnt(6), phase-split K-step, 3-bit slot swizzle.  (local optimum, r4-r6)
template<int EPI>
__device__ __forceinline__ void gemm_body(const ushort* __restrict__ A, const ushort* __restrict__ Bw,
                                          const float* __restrict__ bias, const float* __restrict__ extra,
                                          float* __restrict__ outf, ushort* __restrict__ outb,
                                          char* lds, int m0, int n0)
{
  const int t = threadIdx.x;           // 0..511
  const int w = t >> 6, lane = t & 63;
  const int wm = w >> 1, wn = w & 1;   // 4M x 2N wave grid
  const int rA = lane & 15, g = lane >> 4;

  const ushort* srcA[4]; int ldsA[4];
#pragma unroll
  for (int j = 0; j < 4; j++) {
    int L = (t + j*512) * 16;
    int U = L ^ (((L >> 7) & 7) << 4);
    srcA[j] = A + (size_t)(m0 + (U >> 7))*512 + ((U & 127) >> 1);
    ldsA[j] = L;
  }
  const ushort* srcB[2]; int ldsB[2];
#pragma unroll
  for (int j = 0; j < 2; j++) {
    int L = (t + j*512) * 16;
    int U = L ^ (((L >> 7) & 7) << 4);
    srcB[j] = Bw + (size_t)(n0 + (U >> 7))*512 + ((U & 127) >> 1);
    ldsB[j] = 32768 + L;
  }

#define STAGE_A(ti) do { char* bb_ = lds + ((ti) % 3) * 49152; \
    _Pragma("unroll") \
    for (int j = 0; j < 4; j++) gld16(bb_ + ldsA[j], srcA[j] + (ti)*64); } while (0)
#define STAGE_B(ti) do { char* bb_ = lds + ((ti) % 3) * 49152; \
    _Pragma("unroll") \
    for (int j = 0; j < 2; j++) gld16(bb_ + ldsB[j], srcB[j] + (ti)*64); } while (0)

  STAGE_A(0); STAGE_B(0);
  STAGE_A(1); STAGE_B(1);

  f32x4 acc[4][4] = {};
  for (int i = 0; i < 8; i++) {
    if (i < 7) asm volatile("s_waitcnt vmcnt(6)" ::: "memory");
    else       asm volatile("s_waitcnt vmcnt(0)" ::: "memory");
    __builtin_amdgcn_s_barrier();
    __builtin_amdgcn_sched_barrier(0);
    const char* bufc = lds + (i % 3) * 49152;

    bf16x8 afA[4], bfA[4];
#pragma unroll
    for (int m = 0; m < 4; m++) {
      int row = wm*64 + m*16 + rA;
      afA[m] = *(const bf16x8*)(bufc + ((row*128 + g*16) ^ ((row & 7) << 4)));
    }
#pragma unroll
    for (int n = 0; n < 4; n++) {
      int row = wn*64 + n*16 + rA;
      bfA[n] = *(const bf16x8*)(bufc + 32768 + ((row*128 + g*16) ^ ((row & 7) << 4)));
    }
    if (i < 6) STAGE_A(i + 2);
    __builtin_amdgcn_s_barrier();
    __builtin_amdgcn_sched_barrier(0);

    bf16x8 afB[4], bfB[4];
#pragma unroll
    for (int m = 0; m < 4; m++) {
      int row = wm*64 + m*16 + rA;
      afB[m] = *(const bf16x8*)(bufc + ((row*128 + 64 + g*16) ^ ((row & 7) << 4)));
    }
#pragma unroll
    for (int n = 0; n < 4; n++) {
      int row = wn*64 + n*16 + rA;
      bfB[n] = *(const bf16x8*)(bufc + 32768 + ((row*128 + 64 + g*16) ^ ((row & 7) << 4)));
    }
    if (i < 6) STAGE_B(i + 2);
    __builtin_amdgcn_s_setprio(1);
#pragma unroll
    for (int m = 0; m < 4; m++)
#pragma unroll
      for (int n = 0; n < 4; n++)
        acc[m][n] = __builtin_amdgcn_mfma_f32_16x16x32_bf16(afA[m], bfA[n], acc[m][n], 0, 0, 0);
    __builtin_amdgcn_s_setprio(0);
    __builtin_amdgcn_s_barrier();
    __builtin_amdgcn_sched_barrier(0);

    __builtin_amdgcn_s_setprio(1);
#pragma unroll
    for (int m = 0; m < 4; m++)
#pragma unroll
      for (int n = 0; n < 4; n++)
        acc[m][n] = __builtin_amdgcn_mfma_f32_16x16x32_bf16(afB[m], bfB[n], acc[m][n], 0, 0, 0);
    __builtin_amdgcn_s_setprio(0);
  }
#undef STAGE_A
#undef STAGE_B

#pragma unroll
  for (int m = 0; m < 4; m++)
#pragma unroll
    for (int n = 0; n < 4; n++) {
      int col = n0 + wn*64 + n*16 + rA;
      float bb = bias[col];
      if (EPI == 4) {
        int b = m0 >> 9, k0 = m0 & 511;
        int hh = col >> 6, dl = col & 63;
        int kg = k0 + wm*64 + m*16 + g*4;
        float v0 = acc[m][n][0] + bb, v1 = acc[m][n][1] + bb;
        float v2 = acc[m][n][2] + bb, v3 = acc[m][n][3] + bb;
        uint2 pk;
        pk.x = (uint32_t)f2b(v0) | ((uint32_t)f2b(v1) << 16);
        pk.y = (uint32_t)f2b(v2) | ((uint32_t)f2b(v3) << 16);
        *(uint2*)(outb + ((size_t)((b*8 + hh)*64 + dl)*512 + kg)) = pk;
      } else {
#pragma unroll
        for (int r = 0; r < 4; r++) {
          int row = m0 + wm*64 + m*16 + g*4 + r;
          size_t idx = (size_t)row*512 + col;
          float v = acc[m][n][r] + bb;
          if (EPI == 0)      outb[idx] = f2b(v);
          else if (EPI == 1) { float o = extra[idx] + v; outf[idx] = o; outb[idx] = f2b(o); }
          else if (EPI == 2) outb[idx] = f2b(v > 0.f ? v : 0.f);
          else               outf[idx] += v;
        }
      }
    }
}

template<int EPI>
__global__ __launch_bounds__(512, 2)
void k_gemm(const ushort* __restrict__ A, const ushort* __restrict__ Bw,
            const float* __restrict__ bias, const float* __restrict__ extra,
            float* __restrict__ outf, ushort* __restrict__ outb)
{
  __shared__ __align__(16) char lds[3*49152];   // 144 KB
  gemm_body<EPI>(A, Bw, bias, extra, outf, outb, lds, blockIdx.x*256, blockIdx.y*128);
}

__global__ __launch_bounds__(512, 2)
void k_gemm_qkv(const ushort* __restrict__ Qb, const ushort* __restrict__ Kb,
                const ushort* __restrict__ Wb, const float* __restrict__ bq,
                const float* __restrict__ bk, const float* __restrict__ bvv,
                ushort* __restrict__ qkout, ushort* __restrict__ vpT)
{
  __shared__ __align__(16) char lds[3*49152];
  int z = blockIdx.z;
  if (z == 2) {
    gemm_body<4>(Kb, Wb + 2*(size_t)262144, bvv, nullptr, nullptr,
                 vpT, lds, blockIdx.x*256, blockIdx.y*128);
  } else {
    const ushort* A = (z == 0) ? Qb : Kb;
    const float* bias = (z == 0) ? bq : bk;
    gemm_body<0>(A, Wb + (size_t)z*262144, bias, nullptr, nullptr,
                 qkout + (size_t)z*8388608, lds, blockIdx.x*256, blockIdx.y*128);
  }
}

// ---------------- fused attention: zinv (pass1) + PV (pass2), one block per (b,h) ----------------
// 512 threads / 8 waves.  LDS 160KB: kt [512k][64d] (64K) + vt [64d][512k] (64K) +
// qpr 32K time-shared {pass1: 2x[128q][64d] Q-dbuf | pass2: 8x 4KB wave-private P}.
// K/V staged ONCE; pass1 counted-vmcnt Q pipeline; zinv handed off via global scratch;
// pass2 has NO barriers (P wave-private, K/V resident).
__global__ __launch_bounds__(512, 2)
void k_att2(const ushort* __restrict__ qp, const ushort* __restrict__ kp,
            const ushort* __restrict__ vpT, float* __restrict__ zinv,
            ushort* __restrict__ attn)
{
  __shared__ __align__(16) char kt[65536];
  __shared__ __align__(16) char vt[65536];
  __shared__ __align__(16) char qpr[32768];
  int bh = blockIdx.x;
  int b = bh >> 3, h = bh & 7;
  int t = threadIdx.x, w = t >> 6, lane = t & 63;
  int rA = lane & 15, g = lane >> 4;
  const ushort* kbase = kp + (size_t)(b*512)*512 + h*64;
  const ushort* qbase = qp + (size_t)(b*512)*512 + h*64;
  const ushort* vbase = vpT + (size_t)bh*64*512;

  // ---- issue all stages: K(8/thread), Q0(2), Q1(2), V(8) ----
#pragma unroll
  for (int i = 0; i < 8; i++) {          // K: [512][64] swizzled slot^(k&7)
    int c = i*512 + t; int row = c >> 3, sl = c & 7;
    gld16(kt + c*16, kbase + (size_t)row*512 + ((sl ^ (row & 7))*8));
  }
#define STAGE_Q(buf, qb) do { \
    _Pragma("unroll") \
    for (int i = 0; i < 2; i++) { \
      int c = i*512 + t; int row = c >> 3, sl = c & 7; \
      gld16(qpr + (buf)*16384 + c*16, \
            qbase + (size_t)((qb)*128 + row)*512 + ((sl ^ (row & 7))*8)); } } while (0)
  STAGE_Q(0, 0);
  STAGE_Q(1, 1);
#pragma unroll
  for (int i = 0; i < 8; i++) {          // V: [64][512] swizzled slot64 low3 ^ (d&7)
    int c = i*512 + t; int d = c >> 6, sl = c & 63;
    gld16(vt + c*16, vbase + (size_t)d*512 + ((sl ^ (d & 7))*8));
  }

  // ---- pass 1: zinv[k] = 1/sum_q exp(s*scale); wave owns k in [w*64, w*64+64) ----
  asm volatile("s_waitcnt vmcnt(10)" ::: "memory");   // K + Q0 landed (Q1,V in flight)
  __builtin_amdgcn_s_barrier();
  __builtin_amdgcn_sched_barrier(0);
  bf16x8 kf[4][2];
#pragma unroll
  for (int n = 0; n < 4; n++)
#pragma unroll
    for (int ks = 0; ks < 2; ks++) {
      int k = w*64 + n*16 + rA;
      kf[n][ks] = *(const bf16x8*)(kt + k*128 + (((ks*4 + g) ^ (k & 7))*16));
    }
  float Zacc[4] = {0.f, 0.f, 0.f, 0.f};
  for (int qb = 0; qb < 4; qb++) {
    if (qb == 1)      { asm volatile("s_waitcnt vmcnt(10)" ::: "memory"); }  // Q1 (V+Q2 out)
    else if (qb == 2) { asm volatile("s_waitcnt vmcnt(2)" ::: "memory"); }   // Q2 (Q3 out)
    else if (qb == 3) { asm volatile("s_waitcnt vmcnt(0)" ::: "memory"); }   // Q3
    if (qb) { __builtin_amdgcn_s_barrier(); __builtin_amdgcn_sched_barrier(0); }
    const char* qtb = qpr + (qb & 1)*16384;
    f32x4 acc[8][4] = {};
#pragma unroll
    for (int ks = 0; ks < 2; ks++) {
      bf16x8 af[8];
#pragma unroll
      for (int m = 0; m < 8; m++) {
        int q = m*16 + rA;
        af[m] = *(const bf16x8*)(qtb + q*128 + (((ks*4 + g) ^ (q & 7))*16));
      }
      __builtin_amdgcn_s_setprio(1);
#pragma unroll
      for (int m = 0; m < 8; m++)
#pragma unroll
        for (int n = 0; n < 4; n++)
          acc[m][n] = __builtin_amdgcn_mfma_f32_16x16x32_bf16(af[m], kf[n][ks], acc[m][n], 0, 0, 0);
      __builtin_amdgcn_s_setprio(0);
    }
    if (qb < 3) __builtin_amdgcn_s_barrier();   // all waves done reading qtb
    if (qb < 2) STAGE_Q(qb & 1, qb + 2);        // restage freed buffer
#pragma unroll
    for (int m = 0; m < 8; m++)                 // exp-sum overlaps staging DMA
#pragma unroll
      for (int n = 0; n < 4; n++) {
        float s = 0.f;
#pragma unroll
        for (int r = 0; r < 4; r++) s += __expf(acc[m][n][r] * SCALE_);
        Zacc[n] += s;
      }
  }
#undef STAGE_Q
#pragma unroll
  for (int n = 0; n < 4; n++) {
    float v = Zacc[n];
    v += __shfl_xor(v, 16);
    v += __shfl_xor(v, 32);
    if (lane < 16) zinv[(size_t)bh*512 + w*64 + n*16 + lane] = 1.0f / v;
  }
  asm volatile("s_waitcnt vmcnt(0)" ::: "memory");    // zinv stores + V staged drained
  __builtin_amdgcn_s_barrier();
  __builtin_amdgcn_sched_barrier(0);

  // ---- pass 2: attn rows; wave owns q in [w*64, w*64+64); NO barriers ----
  bf16x8 qf[4][2];
#pragma unroll
  for (int m = 0; m < 4; m++)
#pragma unroll
    for (int ks = 0; ks < 2; ks++)
      qf[m][ks] = *(const bf16x8*)(qbase + (size_t)(w*64 + m*16 + rA)*512 + ks*32 + g*8);
  char* Pw = qpr + w*4096;
  const float* zb = zinv + (size_t)bh*512;
  f32x4 oacc[4][4] = {};
  for (int kc = 0; kc < 16; kc++) {
    f32x4 sacc[2][4] = {};
#pragma unroll
    for (int ks = 0; ks < 2; ks++) {
      bf16x8 kfr[2];
#pragma unroll
      for (int kn = 0; kn < 2; kn++) {
        int k = kc*32 + kn*16 + rA;
        kfr[kn] = *(const bf16x8*)(kt + k*128 + (((ks*4 + g) ^ (k & 7))*16));
      }
      __builtin_amdgcn_s_setprio(1);
#pragma unroll
      for (int kn = 0; kn < 2; kn++)
#pragma unroll
        for (int m = 0; m < 4; m++)
          sacc[kn][m] = __builtin_amdgcn_mfma_f32_16x16x32_bf16(kfr[kn], qf[m][ks], sacc[kn][m], 0, 0, 0);
      __builtin_amdgcn_s_setprio(0);
    }
#pragma unroll
    for (int kn = 0; kn < 2; kn++) {
      f32x4 zv = *(const f32x4*)(zb + kc*32 + kn*16 + g*4);
#pragma unroll
      for (int m = 0; m < 4; m++) {
        float e0 = __expf(sacc[kn][m][0] * SCALE_) * zv[0];
        float e1 = __expf(sacc[kn][m][1] * SCALE_) * zv[1];
        float e2 = __expf(sacc[kn][m][2] * SCALE_) * zv[2];
        float e3 = __expf(sacc[kn][m][3] * SCALE_) * zv[3];
        uint2 pk; pk.x = cvtpk(e0, e1); pk.y = cvtpk(e2, e3);
        int q = m*16 + rA;
        *(uint2*)(Pw + q*64 + ((kn*32 + g*8) ^ ((q & 3) << 4))) = pk;
      }
    }
    bf16x8 pa[4], vb[4];
#pragma unroll
    for (int m = 0; m < 4; m++) {
      int q = m*16 + rA;
      pa[m] = *(const bf16x8*)(Pw + q*64 + ((g*16) ^ ((q & 3) << 4)));
    }
#pragma unroll
    for (int n = 0; n < 4; n++) {
      int d = n*16 + rA;
      vb[n] = *(const bf16x8*)(vt + d*1024 + ((kc*64 + g*16) ^ ((d & 7) << 4)));
    }
    __builtin_amdgcn_s_setprio(1);
#pragma unroll
    for (int m = 0; m < 4; m++)
#pragma unroll
      for (int n = 0; n < 4; n++)
        oacc[m][n] = __builtin_amdgcn_mfma_f32_16x16x32_bf16(pa[m], vb[n], oacc[m][n], 0, 0, 0);
    __builtin_amdgcn_s_setprio(0);
  }
#pragma unroll
  for (int m = 0; m < 4; m++)
#pragma unroll
    for (int n = 0; n < 4; n++)
#pragma unroll
      for (int r = 0; r < 4; r++) {
        int q = w*64 + m*16 + g*4 + r;
        int dcol = h*64 + n*16 + rA;
        attn[(size_t)(b*512 + q)*512 + dcol] = f2b(oacc[m][n][r]);
      }
}

// ---------------- host launcher ----------------
extern "C" void kernel_launch(void* const* d_in, const int* in_sizes, int n_in,
                              void* d_out, int out_size, void* d_ws, size_t ws_size,
                              hipStream_t stream) {
  const float* Q  = (const float*)d_in[0];
  const float* K  = (const float*)d_in[1];
  const float* Wq = (const float*)d_in[2];
  const float* bq = (const float*)d_in[3];
  const float* Wk = (const float*)d_in[4];
  const float* bk = (const float*)d_in[5];
  const float* Wv = (const float*)d_in[6];
  const float* bv = (const float*)d_in[7];
  const float* Wo = (const float*)d_in[8];
  const float* bo = (const float*)d_in[9];
  const float* W1 = (const float*)d_in[10];
  const float* b1 = (const float*)d_in[11];
  const float* W2 = (const float*)d_in[12];
  const float* b2 = (const float*)d_in[13];
  float* out = (float*)d_out;

  const size_t SZ = (size_t)16384 * 512;
  ushort* Qb   = (ushort*)d_ws;                 // later reused as attn
  ushort* Kb   = Qb + SZ;                       // later reused as outb
  ushort* qp   = Kb + SZ;
  ushort* kp   = qp + SZ;
  ushort* vpT  = kp + SZ;                       // v-projection, transposed; later reused as h1
  ushort* Wb   = vpT + SZ;
  float*  zinv = (float*)(Wb + 6 * (size_t)262144);
  ushort* attn = Qb;
  ushort* outb = Kb;
  ushort* h1   = vpT;

  k_cvt<<<dim3(17920), dim3(256), 0, stream>>>(Q, K, Wq, Wk, Wv, Wo, W1, W2, Qb, Kb, Wb);
  k_gemm_qkv<<<dim3(64, 4, 3), dim3(512), 0, stream>>>(Qb, Kb, Wb, bq, bk, bv, qp, vpT);
  k_att2<<<dim3(256), dim3(512), 0, stream>>>(qp, kp, vpT, zinv, attn);
  k_gemm<1><<<dim3(64, 4), dim3(512), 0, stream>>>(attn, Wb + 3*(size_t)262144, bo, Q, out, outb);
  k_gemm<2><<<dim3(64, 4), dim3(512), 0, stream>>>(outb, Wb + 4*(size_t)262144, b1, nullptr, nullptr, h1);
  k_gemm<3><<<dim3(64, 4), dim3(512), 0, stream>>>(h1, Wb + 5*(size_t)262144, b2, nullptr, out, nullptr);
}

// Round 8
// 151.505 us; speedup vs baseline: 1.0886x; 1.0337x over previous
//
#include <hip/hip_runtime.h>
#include <stdint.h>

// MAB block: B=32, N=512, D=512, H=8, dh=64.  M = B*N = 16384.
#define SCALE_ 0.044194173824159216f
// scale * log2(e): folded into the q-projection so attention uses exp2 directly.
#define QSC_ (0.044194173824159216f * 1.4426950408889634f)

typedef __attribute__((ext_vector_type(8))) short bf16x8;
typedef __attribute__((ext_vector_type(4))) float f32x4;

__device__ __forceinline__ ushort f2b(float f) {
  union { float f; uint32_t u; } v; v.f = f;
  return (ushort)((v.u + 0x7fffu + ((v.u >> 16) & 1u)) >> 16);  // RNE
}
__device__ __forceinline__ uint32_t cvtpk(float lo, float hi) {
  uint32_t r; asm("v_cvt_pk_bf16_f32 %0, %1, %2" : "=v"(r) : "v"(lo), "v"(hi)); return r;
}
__device__ __forceinline__ float ex2(float x) {          // 2^x (v_exp_f32)
  float r; asm("v_exp_f32 %0, %1" : "=v"(r) : "v"(x)); return r;
}
__device__ __forceinline__ void gld16(void* lds, const void* g) {
  __builtin_amdgcn_global_load_lds(
      (const __attribute__((address_space(1))) uint32_t*)g,
      (__attribute__((address_space(3))) uint32_t*)lds, 16, 0, 0);
}

// ---------------- fp32 -> bf16 convert (Q, K, 6 weights) ----------------
__global__ __launch_bounds__(256)
void k_cvt(const float* __restrict__ Q, const float* __restrict__ K,
           const float* __restrict__ w0, const float* __restrict__ w1,
           const float* __restrict__ w2, const float* __restrict__ w3,
           const float* __restrict__ w4, const float* __restrict__ w5,
           ushort* __restrict__ Qb, ushort* __restrict__ Kb, ushort* __restrict__ Wb)
{
  const long long NQ = 8388608LL, NW = 262144LL;
  long long i = ((long long)blockIdx.x * 256 + threadIdx.x) * 4;
  const float* src; ushort* dst; long long off;
  if (i < NQ)        { src = Q; dst = Qb; off = i; }
  else if (i < 2*NQ) { src = K; dst = Kb; off = i - NQ; }
  else {
    long long j = i - 2*NQ; int seg = (int)(j / NW); off = j - (long long)seg * NW;
    switch (seg) { case 0: src = w0; break; case 1: src = w1; break; case 2: src = w2; break;
                   case 3: src = w3; break; case 4: src = w4; break; default: src = w5; }
    dst = Wb + (size_t)seg * NW;
  }
  float4 v = *(const float4*)(src + off);
  ushort4 o = make_ushort4(f2b(v.x), f2b(v.y), f2b(v.z), f2b(v.w));
  *(ushort4*)(dst + off) = o;
}

// ---------------- GEMM C = A(bf16,[M,512]) @ Bw(bf16,[512,512])^T ----------------
// 256x128 tile, BK=64, 512 threads (8 waves = 4M x 2N).  Triple-buffered LDS,
// counted vmcnt(6), phase-split K-step, 3-bit slot swizzle.  (local optimum, r4-r6)
// EPI0 additionally scales the output by `os` (used to fold QSC_ into q-projection).
template<int EPI>
__device__ __forceinline__ void gemm_body(const ushort* __restrict__ A, const ushort* __restrict__ Bw,
                                          const float* __restrict__ bias, const float* __restrict__ extra,
                                          float* __restrict__ outf, ushort* __restrict__ outb,
                                          char* lds, int m0, int n0, float os)
{
  const int t = threadIdx.x;           // 0..511
  const int w = t >> 6, lane = t & 63;
  const int wm = w >> 1, wn = w & 1;   // 4M x 2N wave grid
  const int rA = lane & 15, g = lane >> 4;

  const ushort* srcA[4]; int ldsA[4];
#pragma unroll
  for (int j = 0; j < 4; j++) {
    int L = (t + j*512) * 16;
    int U = L ^ (((L >> 7) & 7) << 4);
    srcA[j] = A + (size_t)(m0 + (U >> 7))*512 + ((U & 127) >> 1);
    ldsA[j] = L;
  }
  const ushort* srcB[2]; int ldsB[2];
#pragma unroll
  for (int j = 0; j < 2; j++) {
    int L = (t + j*512) * 16;
    int U = L ^ (((L >> 7) & 7) << 4);
    srcB[j] = Bw + (size_t)(n0 + (U >> 7))*512 + ((U & 127) >> 1);
    ldsB[j] = 32768 + L;
  }

#define STAGE_A(ti) do { char* bb_ = lds + ((ti) % 3) * 49152; \
    _Pragma("unroll") \
    for (int j = 0; j < 4; j++) gld16(bb_ + ldsA[j], srcA[j] + (ti)*64); } while (0)
#define STAGE_B(ti) do { char* bb_ = lds + ((ti) % 3) * 49152; \
    _Pragma("unroll") \
    for (int j = 0; j < 2; j++) gld16(bb_ + ldsB[j], srcB[j] + (ti)*64); } while (0)

  STAGE_A(0); STAGE_B(0);
  STAGE_A(1); STAGE_B(1);

  f32x4 acc[4][4] = {};
  for (int i = 0; i < 8; i++) {
    if (i < 7) asm volatile("s_waitcnt vmcnt(6)" ::: "memory");
    else       asm volatile("s_waitcnt vmcnt(0)" ::: "memory");
    __builtin_amdgcn_s_barrier();
    __builtin_amdgcn_sched_barrier(0);
    const char* bufc = lds + (i % 3) * 49152;

    bf16x8 afA[4], bfA[4];
#pragma unroll
    for (int m = 0; m < 4; m++) {
      int row = wm*64 + m*16 + rA;
      afA[m] = *(const bf16x8*)(bufc + ((row*128 + g*16) ^ ((row & 7) << 4)));
    }
#pragma unroll
    for (int n = 0; n < 4; n++) {
      int row = wn*64 + n*16 + rA;
      bfA[n] = *(const bf16x8*)(bufc + 32768 + ((row*128 + g*16) ^ ((row & 7) << 4)));
    }
    if (i < 6) STAGE_A(i + 2);
    __builtin_amdgcn_s_barrier();
    __builtin_amdgcn_sched_barrier(0);

    bf16x8 afB[4], bfB[4];
#pragma unroll
    for (int m = 0; m < 4; m++) {
      int row = wm*64 + m*16 + rA;
      afB[m] = *(const bf16x8*)(bufc + ((row*128 + 64 + g*16) ^ ((row & 7) << 4)));
    }
#pragma unroll
    for (int n = 0; n < 4; n++) {
      int row = wn*64 + n*16 + rA;
      bfB[n] = *(const bf16x8*)(bufc + 32768 + ((row*128 + 64 + g*16) ^ ((row & 7) << 4)));
    }
    if (i < 6) STAGE_B(i + 2);
    __builtin_amdgcn_s_setprio(1);
#pragma unroll
    for (int m = 0; m < 4; m++)
#pragma unroll
      for (int n = 0; n < 4; n++)
        acc[m][n] = __builtin_amdgcn_mfma_f32_16x16x32_bf16(afA[m], bfA[n], acc[m][n], 0, 0, 0);
    __builtin_amdgcn_s_setprio(0);
    __builtin_amdgcn_s_barrier();
    __builtin_amdgcn_sched_barrier(0);

    __builtin_amdgcn_s_setprio(1);
#pragma unroll
    for (int m = 0; m < 4; m++)
#pragma unroll
      for (int n = 0; n < 4; n++)
        acc[m][n] = __builtin_amdgcn_mfma_f32_16x16x32_bf16(afB[m], bfB[n], acc[m][n], 0, 0, 0);
    __builtin_amdgcn_s_setprio(0);
  }
#undef STAGE_A
#undef STAGE_B

#pragma unroll
  for (int m = 0; m < 4; m++)
#pragma unroll
    for (int n = 0; n < 4; n++) {
      int col = n0 + wn*64 + n*16 + rA;
      float bb = bias[col];
      if (EPI == 4) {
        int b = m0 >> 9, k0 = m0 & 511;
        int hh = col >> 6, dl = col & 63;
        int kg = k0 + wm*64 + m*16 + g*4;
        float v0 = acc[m][n][0] + bb, v1 = acc[m][n][1] + bb;
        float v2 = acc[m][n][2] + bb, v3 = acc[m][n][3] + bb;
        uint2 pk;
        pk.x = (uint32_t)f2b(v0) | ((uint32_t)f2b(v1) << 16);
        pk.y = (uint32_t)f2b(v2) | ((uint32_t)f2b(v3) << 16);
        *(uint2*)(outb + ((size_t)((b*8 + hh)*64 + dl)*512 + kg)) = pk;
      } else {
#pragma unroll
        for (int r = 0; r < 4; r++) {
          int row = m0 + wm*64 + m*16 + g*4 + r;
          size_t idx = (size_t)row*512 + col;
          float v = acc[m][n][r] + bb;
          if (EPI == 0)      outb[idx] = f2b(v * os);
          else if (EPI == 1) { float o = extra[idx] + v; outf[idx] = o; outb[idx] = f2b(o); }
          else if (EPI == 2) outb[idx] = f2b(v > 0.f ? v : 0.f);
          else               outf[idx] += v;
        }
      }
    }
}

template<int EPI>
__global__ __launch_bounds__(512, 2)
void k_gemm(const ushort* __restrict__ A, const ushort* __restrict__ Bw,
            const float* __restrict__ bias, const float* __restrict__ extra,
            float* __restrict__ outf, ushort* __restrict__ outb)
{
  __shared__ __align__(16) char lds[3*49152];   // 144 KB
  gemm_body<EPI>(A, Bw, bias, extra, outf, outb, lds, blockIdx.x*256, blockIdx.y*128, 1.0f);
}

__global__ __launch_bounds__(512, 2)
void k_gemm_qkv(const ushort* __restrict__ Qb, const ushort* __restrict__ Kb,
                const ushort* __restrict__ Wb, const float* __restrict__ bq,
                const float* __restrict__ bk, const float* __restrict__ bvv,
                ushort* __restrict__ qkout, ushort* __restrict__ vpT)
{
  __shared__ __align__(16) char lds[3*49152];
  int z = blockIdx.z;
  if (z == 2) {
    gemm_body<4>(Kb, Wb + 2*(size_t)262144, bvv, nullptr, nullptr,
                 vpT, lds, blockIdx.x*256, blockIdx.y*128, 1.0f);
  } else {
    const ushort* A = (z == 0) ? Qb : Kb;
    const float* bias = (z == 0) ? bq : bk;
    float os = (z == 0) ? QSC_ : 1.0f;          // fold scale*log2e into q-projection
    gemm_body<0>(A, Wb + (size_t)z*262144, bias, nullptr, nullptr,
                 qkout + (size_t)z*8388608, lds, blockIdx.x*256, blockIdx.y*128, os);
  }
}

// ---------------- fused attention: zinv (pass1) + PV (pass2), one block per (b,h) ----------------
// q is pre-scaled by QSC_ so s = qk dot is already in exp2 domain: e = 2^s via v_exp_f32.
__global__ __launch_bounds__(512, 2)
void k_att2(const ushort* __restrict__ qp, const ushort* __restrict__ kp,
            const ushort* __restrict__ vpT, float* __restrict__ zinv,
            ushort* __restrict__ attn)
{
  __shared__ __align__(16) char kt[65536];
  __shared__ __align__(16) char vt[65536];
  __shared__ __align__(16) char qpr[32768];
  int bh = blockIdx.x;
  int b = bh >> 3, h = bh & 7;
  int t = threadIdx.x, w = t >> 6, lane = t & 63;
  int rA = lane & 15, g = lane >> 4;
  const ushort* kbase = kp + (size_t)(b*512)*512 + h*64;
  const ushort* qbase = qp + (size_t)(b*512)*512 + h*64;
  const ushort* vbase = vpT + (size_t)bh*64*512;

  // ---- issue all stages: K(8/thread), Q0(2), Q1(2), V(8) ----
#pragma unroll
  for (int i = 0; i < 8; i++) {          // K: [512][64] swizzled slot^(k&7)
    int c = i*512 + t; int row = c >> 3, sl = c & 7;
    gld16(kt + c*16, kbase + (size_t)row*512 + ((sl ^ (row & 7))*8));
  }
#define STAGE_Q(buf, qb) do { \
    _Pragma("unroll") \
    for (int i = 0; i < 2; i++) { \
      int c = i*512 + t; int row = c >> 3, sl = c & 7; \
      gld16(qpr + (buf)*16384 + c*16, \
            qbase + (size_t)((qb)*128 + row)*512 + ((sl ^ (row & 7))*8)); } } while (0)
  STAGE_Q(0, 0);
  STAGE_Q(1, 1);
#pragma unroll
  for (int i = 0; i < 8; i++) {          // V: [64][512] swizzled slot64 low3 ^ (d&7)
    int c = i*512 + t; int d = c >> 6, sl = c & 63;
    gld16(vt + c*16, vbase + (size_t)d*512 + ((sl ^ (d & 7))*8));
  }

  // ---- pass 1: zinv[k] = 1/sum_q 2^s; wave owns k in [w*64, w*64+64) ----
  asm volatile("s_waitcnt vmcnt(10)" ::: "memory");   // K + Q0 landed (Q1,V in flight)
  __builtin_amdgcn_s_barrier();
  __builtin_amdgcn_sched_barrier(0);
  bf16x8 kf[4][2];
#pragma unroll
  for (int n = 0; n < 4; n++)
#pragma unroll
    for (int ks = 0; ks < 2; ks++) {
      int k = w*64 + n*16 + rA;
      kf[n][ks] = *(const bf16x8*)(kt + k*128 + (((ks*4 + g) ^ (k & 7))*16));
    }
  float Zacc[4] = {0.f, 0.f, 0.f, 0.f};
  for (int qb = 0; qb < 4; qb++) {
    if (qb == 1)      { asm volatile("s_waitcnt vmcnt(10)" ::: "memory"); }  // Q1 (V+Q2 out)
    else if (qb == 2) { asm volatile("s_waitcnt vmcnt(2)" ::: "memory"); }   // Q2 (Q3 out)
    else if (qb == 3) { asm volatile("s_waitcnt vmcnt(0)" ::: "memory"); }   // Q3
    if (qb) { __builtin_amdgcn_s_barrier(); __builtin_amdgcn_sched_barrier(0); }
    const char* qtb = qpr + (qb & 1)*16384;
    f32x4 acc[8][4] = {};
#pragma unroll
    for (int ks = 0; ks < 2; ks++) {
      bf16x8 af[8];
#pragma unroll
      for (int m = 0; m < 8; m++) {
        int q = m*16 + rA;
        af[m] = *(const bf16x8*)(qtb + q*128 + (((ks*4 + g) ^ (q & 7))*16));
      }
      __builtin_amdgcn_s_setprio(1);
#pragma unroll
      for (int m = 0; m < 8; m++)
#pragma unroll
        for (int n = 0; n < 4; n++)
          acc[m][n] = __builtin_amdgcn_mfma_f32_16x16x32_bf16(af[m], kf[n][ks], acc[m][n], 0, 0, 0);
      __builtin_amdgcn_s_setprio(0);
    }
    if (qb < 3) __builtin_amdgcn_s_barrier();   // all waves done reading qtb
    if (qb < 2) STAGE_Q(qb & 1, qb + 2);        // restage freed buffer
#pragma unroll
    for (int m = 0; m < 8; m++)                 // exp2-sum overlaps staging DMA
#pragma unroll
      for (int n = 0; n < 4; n++) {
        float s = 0.f;
#pragma unroll
        for (int r = 0; r < 4; r++) s += ex2(acc[m][n][r]);
        Zacc[n] += s;
      }
  }
#undef STAGE_Q
#pragma unroll
  for (int n = 0; n < 4; n++) {
    float v = Zacc[n];
    v += __shfl_xor(v, 16);
    v += __shfl_xor(v, 32);
    if (lane < 16) zinv[(size_t)bh*512 + w*64 + n*16 + lane] = 1.0f / v;
  }
  asm volatile("s_waitcnt vmcnt(0)" ::: "memory");    // zinv stores + V staged drained
  __builtin_amdgcn_s_barrier();
  __builtin_amdgcn_sched_barrier(0);

  // ---- pass 2: attn rows; wave owns q in [w*64, w*64+64); NO barriers ----
  bf16x8 qf[4][2];
#pragma unroll
  for (int m = 0; m < 4; m++)
#pragma unroll
    for (int ks = 0; ks < 2; ks++)
      qf[m][ks] = *(const bf16x8*)(qbase + (size_t)(w*64 + m*16 + rA)*512 + ks*32 + g*8);
  char* Pw = qpr + w*4096;
  const float* zb = zinv + (size_t)bh*512;
  f32x4 oacc[4][4] = {};
  for (int kc = 0; kc < 16; kc++) {
    f32x4 sacc[2][4] = {};
#pragma unroll
    for (int ks = 0; ks < 2; ks++) {
      bf16x8 kfr[2];
#pragma unroll
      for (int kn = 0; kn < 2; kn++) {
        int k = kc*32 + kn*16 + rA;
        kfr[kn] = *(const bf16x8*)(kt + k*128 + (((ks*4 + g) ^ (k & 7))*16));
      }
      __builtin_amdgcn_s_setprio(1);
#pragma unroll
      for (int kn = 0; kn < 2; kn++)
#pragma unroll
        for (int m = 0; m < 4; m++)
          sacc[kn][m] = __builtin_amdgcn_mfma_f32_16x16x32_bf16(kfr[kn], qf[m][ks], sacc[kn][m], 0, 0, 0);
      __builtin_amdgcn_s_setprio(0);
    }
#pragma unroll
    for (int kn = 0; kn < 2; kn++) {
      f32x4 zv = *(const f32x4*)(zb + kc*32 + kn*16 + g*4);
#pragma unroll
      for (int m = 0; m < 4; m++) {
        float e0 = ex2(sacc[kn][m][0]) * zv[0];
        float e1 = ex2(sacc[kn][m][1]) * zv[1];
        float e2 = ex2(sacc[kn][m][2]) * zv[2];
        float e3 = ex2(sacc[kn][m][3]) * zv[3];
        uint2 pk; pk.x = cvtpk(e0, e1); pk.y = cvtpk(e2, e3);
        int q = m*16 + rA;
        *(uint2*)(Pw + q*64 + ((kn*32 + g*8) ^ ((q & 6) << 3))) = pk;
      }
    }
    bf16x8 pa[4], vb[4];
#pragma unroll
    for (int m = 0; m < 4; m++) {
      int q = m*16 + rA;
      pa[m] = *(const bf16x8*)(Pw + q*64 + ((g*16) ^ ((q & 6) << 3)));
    }
#pragma unroll
    for (int n = 0; n < 4; n++) {
      int d = n*16 + rA;
      vb[n] = *(const bf16x8*)(vt + d*1024 + ((kc*64 + g*16) ^ ((d & 7) << 4)));
    }
    __builtin_amdgcn_s_setprio(1);
#pragma unroll
    for (int m = 0; m < 4; m++)
#pragma unroll
      for (int n = 0; n < 4; n++)
        oacc[m][n] = __builtin_amdgcn_mfma_f32_16x16x32_bf16(pa[m], vb[n], oacc[m][n], 0, 0, 0);
    __builtin_amdgcn_s_setprio(0);
  }
#pragma unroll
  for (int m = 0; m < 4; m++)
#pragma unroll
    for (int n = 0; n < 4; n++)
#pragma unroll
      for (int r = 0; r < 4; r++) {
        int q = w*64 + m*16 + g*4 + r;
        int dcol = h*64 + n*16 + rA;
        attn[(size_t)(b*512 + q)*512 + dcol] = f2b(oacc[m][n][r]);
      }
}

// ---------------- host launcher ----------------
extern "C" void kernel_launch(void* const* d_in, const int* in_sizes, int n_in,
                              void* d_out, int out_size, void* d_ws, size_t ws_size,
                              hipStream_t stream) {
  const float* Q  = (const float*)d_in[0];
  const float* K  = (const float*)d_in[1];
  const float* Wq = (const float*)d_in[2];
  const float* bq = (const float*)d_in[3];
  const float* Wk = (const float*)d_in[4];
  const float* bk = (const float*)d_in[5];
  const float* Wv = (const float*)d_in[6];
  const float* bv = (const float*)d_in[7];
  const float* Wo = (const float*)d_in[8];
  const float* bo = (const float*)d_in[9];
  const float* W1 = (const float*)d_in[10];
  const float* b1 = (const float*)d_in[11];
  const float* W2 = (const float*)d_in[12];
  const float* b2 = (const float*)d_in[13];
  float* out = (float*)d_out;

  const size_t SZ = (size_t)16384 * 512;
  ushort* Qb   = (ushort*)d_ws;                 // later reused as attn
  ushort* Kb   = Qb + SZ;                       // later reused as outb
  ushort* qp   = Kb + SZ;
  ushort* kp   = qp + SZ;
  ushort* vpT  = kp + SZ;                       // v-projection, transposed; later reused as h1
  ushort* Wb   = vpT + SZ;
  float*  zinv = (float*)(Wb + 6 * (size_t)262144);
  ushort* attn = Qb;
  ushort* outb = Kb;
  ushort* h1   = vpT;

  k_cvt<<<dim3(17920), dim3(256), 0, stream>>>(Q, K, Wq, Wk, Wv, Wo, W1, W2, Qb, Kb, Wb);
  k_gemm_qkv<<<dim3(64, 4, 3), dim3(512), 0, stream>>>(Qb, Kb, Wb, bq, bk, bv, qp, vpT);
  k_att2<<<dim3(256), dim3(512), 0, stream>>>(qp, kp, vpT, zinv, attn);
  k_gemm<1><<<dim3(64, 4), dim3(512), 0, stream>>>(attn, Wb + 3*(size_t)262144, bo, Q, out, outb);
  k_gemm<2><<<dim3(64, 4), dim3(512), 0, stream>>>(outb, Wb + 4*(size_t)262144, b1, nullptr, nullptr, h1);
  k_gemm<3><<<dim3(64, 4), dim3(512), 0, stream>>>(h1, Wb + 5*(size_t)262144, b2, nullptr, out, nullptr);
}

// Round 9
// 148.301 us; speedup vs baseline: 1.1121x; 1.0216x over previous
//
#include <hip/hip_runtime.h>
#include <stdint.h>

// MAB block: B=32, N=512, D=512, H=8, dh=64.  M = B*N = 16384.
#define SCALE_ 0.044194173824159216f
// scale * log2(e): folded into the q-projection so attention uses exp2 directly.
#define QSC_ (0.044194173824159216f * 1.4426950408889634f)

typedef __attribute__((ext_vector_type(8))) short bf16x8;
typedef __attribute__((ext_vector_type(4))) float f32x4;
typedef __attribute__((ext_vector_type(16))) float f32x16;
typedef __attribute__((ext_vector_type(2))) unsigned int uint2v;

__device__ __forceinline__ ushort f2b(float f) {
  union { float f; uint32_t u; } v; v.f = f;
  return (ushort)((v.u + 0x7fffu + ((v.u >> 16) & 1u)) >> 16);  // RNE
}
__device__ __forceinline__ uint32_t cvtpk(float lo, float hi) {
  uint32_t r; asm("v_cvt_pk_bf16_f32 %0, %1, %2" : "=v"(r) : "v"(lo), "v"(hi)); return r;
}
__device__ __forceinline__ float ex2(float x) {          // 2^x (v_exp_f32)
  float r; asm("v_exp_f32 %0, %1" : "=v"(r) : "v"(x)); return r;
}
__device__ __forceinline__ void gld16(void* lds, const void* g) {
  __builtin_amdgcn_global_load_lds(
      (const __attribute__((address_space(1))) uint32_t*)g,
      (__attribute__((address_space(3))) uint32_t*)lds, 16, 0, 0);
}

// ---------------- fp32 -> bf16 convert (Q, K, 6 weights) ----------------
__global__ __launch_bounds__(256)
void k_cvt(const float* __restrict__ Q, const float* __restrict__ K,
           const float* __restrict__ w0, const float* __restrict__ w1,
           const float* __restrict__ w2, const float* __restrict__ w3,
           const float* __restrict__ w4, const float* __restrict__ w5,
           ushort* __restrict__ Qb, ushort* __restrict__ Kb, ushort* __restrict__ Wb)
{
  const long long NQ = 8388608LL, NW = 262144LL;
  long long i = ((long long)blockIdx.x * 256 + threadIdx.x) * 4;
  const float* src; ushort* dst; long long off;
  if (i < NQ)        { src = Q; dst = Qb; off = i; }
  else if (i < 2*NQ) { src = K; dst = Kb; off = i - NQ; }
  else {
    long long j = i - 2*NQ; int seg = (int)(j / NW); off = j - (long long)seg * NW;
    switch (seg) { case 0: src = w0; break; case 1: src = w1; break; case 2: src = w2; break;
                   case 3: src = w3; break; case 4: src = w4; break; default: src = w5; }
    dst = Wb + (size_t)seg * NW;
  }
  float4 v = *(const float4*)(src + off);
  ushort4 o = make_ushort4(f2b(v.x), f2b(v.y), f2b(v.z), f2b(v.w));
  *(ushort4*)(dst + off) = o;
}

// ---------------- GEMM C = A(bf16,[M,512]) @ Bw(bf16,[512,512])^T ----------------
// 256x128 tile, BK=64, 512 threads (8 waves = 4M x 2N).  Triple-buffered LDS,
// counted vmcnt(6), phase-split K-step, 3-bit slot swizzle.  (local optimum, r4-r6)
template<int EPI>
__device__ __forceinline__ void gemm_body(const ushort* __restrict__ A, const ushort* __restrict__ Bw,
                                          const float* __restrict__ bias, const float* __restrict__ extra,
                                          float* __restrict__ outf, ushort* __restrict__ outb,
                                          char* lds, int m0, int n0, float os)
{
  const int t = threadIdx.x;           // 0..511
  const int w = t >> 6, lane = t & 63;
  const int wm = w >> 1, wn = w & 1;   // 4M x 2N wave grid
  const int rA = lane & 15, g = lane >> 4;

  const ushort* srcA[4]; int ldsA[4];
#pragma unroll
  for (int j = 0; j < 4; j++) {
    int L = (t + j*512) * 16;
    int U = L ^ (((L >> 7) & 7) << 4);
    srcA[j] = A + (size_t)(m0 + (U >> 7))*512 + ((U & 127) >> 1);
    ldsA[j] = L;
  }
  const ushort* srcB[2]; int ldsB[2];
#pragma unroll
  for (int j = 0; j < 2; j++) {
    int L = (t + j*512) * 16;
    int U = L ^ (((L >> 7) & 7) << 4);
    srcB[j] = Bw + (size_t)(n0 + (U >> 7))*512 + ((U & 127) >> 1);
    ldsB[j] = 32768 + L;
  }

#define STAGE_A(ti) do { char* bb_ = lds + ((ti) % 3) * 49152; \
    _Pragma("unroll") \
    for (int j = 0; j < 4; j++) gld16(bb_ + ldsA[j], srcA[j] + (ti)*64); } while (0)
#define STAGE_B(ti) do { char* bb_ = lds + ((ti) % 3) * 49152; \
    _Pragma("unroll") \
    for (int j = 0; j < 2; j++) gld16(bb_ + ldsB[j], srcB[j] + (ti)*64); } while (0)

  STAGE_A(0); STAGE_B(0);
  STAGE_A(1); STAGE_B(1);

  f32x4 acc[4][4] = {};
  for (int i = 0; i < 8; i++) {
    if (i < 7) asm volatile("s_waitcnt vmcnt(6)" ::: "memory");
    else       asm volatile("s_waitcnt vmcnt(0)" ::: "memory");
    __builtin_amdgcn_s_barrier();
    __builtin_amdgcn_sched_barrier(0);
    const char* bufc = lds + (i % 3) * 49152;

    bf16x8 afA[4], bfA[4];
#pragma unroll
    for (int m = 0; m < 4; m++) {
      int row = wm*64 + m*16 + rA;
      afA[m] = *(const bf16x8*)(bufc + ((row*128 + g*16) ^ ((row & 7) << 4)));
    }
#pragma unroll
    for (int n = 0; n < 4; n++) {
      int row = wn*64 + n*16 + rA;
      bfA[n] = *(const bf16x8*)(bufc + 32768 + ((row*128 + g*16) ^ ((row & 7) << 4)));
    }
    if (i < 6) STAGE_A(i + 2);
    __builtin_amdgcn_s_barrier();
    __builtin_amdgcn_sched_barrier(0);

    bf16x8 afB[4], bfB[4];
#pragma unroll
    for (int m = 0; m < 4; m++) {
      int row = wm*64 + m*16 + rA;
      afB[m] = *(const bf16x8*)(bufc + ((row*128 + 64 + g*16) ^ ((row & 7) << 4)));
    }
#pragma unroll
    for (int n = 0; n < 4; n++) {
      int row = wn*64 + n*16 + rA;
      bfB[n] = *(const bf16x8*)(bufc + 32768 + ((row*128 + 64 + g*16) ^ ((row & 7) << 4)));
    }
    if (i < 6) STAGE_B(i + 2);
    __builtin_amdgcn_s_setprio(1);
#pragma unroll
    for (int m = 0; m < 4; m++)
#pragma unroll
      for (int n = 0; n < 4; n++)
        acc[m][n] = __builtin_amdgcn_mfma_f32_16x16x32_bf16(afA[m], bfA[n], acc[m][n], 0, 0, 0);
    __builtin_amdgcn_s_setprio(0);
    __builtin_amdgcn_s_barrier();
    __builtin_amdgcn_sched_barrier(0);

    __builtin_amdgcn_s_setprio(1);
#pragma unroll
    for (int m = 0; m < 4; m++)
#pragma unroll
      for (int n = 0; n < 4; n++)
        acc[m][n] = __builtin_amdgcn_mfma_f32_16x16x32_bf16(afB[m], bfB[n], acc[m][n], 0, 0, 0);
    __builtin_amdgcn_s_setprio(0);
  }
#undef STAGE_A
#undef STAGE_B

#pragma unroll
  for (int m = 0; m < 4; m++)
#pragma unroll
    for (int n = 0; n < 4; n++) {
      int col = n0 + wn*64 + n*16 + rA;
      float bb = bias[col];
      if (EPI == 4) {
        int b = m0 >> 9, k0 = m0 & 511;
        int hh = col >> 6, dl = col & 63;
        int kg = k0 + wm*64 + m*16 + g*4;
        float v0 = acc[m][n][0] + bb, v1 = acc[m][n][1] + bb;
        float v2 = acc[m][n][2] + bb, v3 = acc[m][n][3] + bb;
        uint2 pk;
        pk.x = (uint32_t)f2b(v0) | ((uint32_t)f2b(v1) << 16);
        pk.y = (uint32_t)f2b(v2) | ((uint32_t)f2b(v3) << 16);
        *(uint2*)(outb + ((size_t)((b*8 + hh)*64 + dl)*512 + kg)) = pk;
      } else {
#pragma unroll
        for (int r = 0; r < 4; r++) {
          int row = m0 + wm*64 + m*16 + g*4 + r;
          size_t idx = (size_t)row*512 + col;
          float v = acc[m][n][r] + bb;
          if (EPI == 0)      outb[idx] = f2b(v * os);
          else if (EPI == 1) { float o = extra[idx] + v; outf[idx] = o; outb[idx] = f2b(o); }
          else if (EPI == 2) outb[idx] = f2b(v > 0.f ? v : 0.f);
          else               outf[idx] += v;
        }
      }
    }
}

template<int EPI>
__global__ __launch_bounds__(512, 2)
void k_gemm(const ushort* __restrict__ A, const ushort* __restrict__ Bw,
            const float* __restrict__ bias, const float* __restrict__ extra,
            float* __restrict__ outf, ushort* __restrict__ outb)
{
  __shared__ __align__(16) char lds[3*49152];   // 144 KB
  gemm_body<EPI>(A, Bw, bias, extra, outf, outb, lds, blockIdx.x*256, blockIdx.y*128, 1.0f);
}

__global__ __launch_bounds__(512, 2)
void k_gemm_qkv(const ushort* __restrict__ Qb, const ushort* __restrict__ Kb,
                const ushort* __restrict__ Wb, const float* __restrict__ bq,
                const float* __restrict__ bk, const float* __restrict__ bvv,
                ushort* __restrict__ qkout, ushort* __restrict__ vpT)
{
  __shared__ __align__(16) char lds[3*49152];
  int z = blockIdx.z;
  if (z == 2) {
    gemm_body<4>(Kb, Wb + 2*(size_t)262144, bvv, nullptr, nullptr,
                 vpT, lds, blockIdx.x*256, blockIdx.y*128, 1.0f);
  } else {
    const ushort* A = (z == 0) ? Qb : Kb;
    const float* bias = (z == 0) ? bq : bk;
    float os = (z == 0) ? QSC_ : 1.0f;          // fold scale*log2e into q-projection
    gemm_body<0>(A, Wb + (size_t)z*262144, bias, nullptr, nullptr,
                 qkout + (size_t)z*8388608, lds, blockIdx.x*256, blockIdx.y*128, os);
  }
}

// ---------------- fused attention: zinv (pass1, 16x16) + PV (pass2, 32x32 in-register P) ----------------
// One block per (b,h), 512 threads / 8 waves.  LDS: kt 64K + vt 64K + qpr 32K
// {pass1: Q double-buffer | handoff: zl[512] f32 | pass2: nothing (P in registers)}.
// Pass2: swapped QK^T at 32x32x16 -> lane holds 16 P-vals of one q-col, k uniform per
// (reg, lane-half) -> zinv broadcast reads; cvt_pk pairs + permlane32_swap assemble PV
// A-frags directly (T12).  No LDS P traffic, no pass2 barriers.
__global__ __launch_bounds__(512, 2)
void k_att2(const ushort* __restrict__ qp, const ushort* __restrict__ kp,
            const ushort* __restrict__ vpT, float* __restrict__ zinv,
            ushort* __restrict__ attn)
{
  __shared__ __align__(16) char kt[65536];
  __shared__ __align__(16) char vt[65536];
  __shared__ __align__(16) char qpr[32768];
  int bh = blockIdx.x;
  int b = bh >> 3, h = bh & 7;
  int t = threadIdx.x, w = t >> 6, lane = t & 63;
  int rA = lane & 15, g = lane >> 4;
  const ushort* kbase = kp + (size_t)(b*512)*512 + h*64;
  const ushort* qbase = qp + (size_t)(b*512)*512 + h*64;
  const ushort* vbase = vpT + (size_t)bh*64*512;

  // ---- issue all stages: K(8/thread), Q0(2), Q1(2), V(8) ----
#pragma unroll
  for (int i = 0; i < 8; i++) {          // K: [512][64] swizzled slot^(k&7)
    int c = i*512 + t; int row = c >> 3, sl = c & 7;
    gld16(kt + c*16, kbase + (size_t)row*512 + ((sl ^ (row & 7))*8));
  }
#define STAGE_Q(buf, qb) do { \
    _Pragma("unroll") \
    for (int i = 0; i < 2; i++) { \
      int c = i*512 + t; int row = c >> 3, sl = c & 7; \
      gld16(qpr + (buf)*16384 + c*16, \
            qbase + (size_t)((qb)*128 + row)*512 + ((sl ^ (row & 7))*8)); } } while (0)
  STAGE_Q(0, 0);
  STAGE_Q(1, 1);
#pragma unroll
  for (int i = 0; i < 8; i++) {          // V: [64][512] swizzled slot low3 ^ (d&7)
    int c = i*512 + t; int d = c >> 6, sl = c & 63;
    gld16(vt + c*16, vbase + (size_t)d*512 + ((sl ^ (d & 7))*8));
  }

  // ---- pass 1: zl[k] = 1/sum_q 2^s; wave owns k in [w*64, w*64+64) ----
  asm volatile("s_waitcnt vmcnt(10)" ::: "memory");   // K + Q0 landed (Q1,V in flight)
  __builtin_amdgcn_s_barrier();
  __builtin_amdgcn_sched_barrier(0);
  bf16x8 kf[4][2];
#pragma unroll
  for (int n = 0; n < 4; n++)
#pragma unroll
    for (int ks = 0; ks < 2; ks++) {
      int k = w*64 + n*16 + rA;
      kf[n][ks] = *(const bf16x8*)(kt + k*128 + (((ks*4 + g) ^ (k & 7))*16));
    }
  float Zacc[4] = {0.f, 0.f, 0.f, 0.f};
  for (int qb = 0; qb < 4; qb++) {
    if (qb == 1)      { asm volatile("s_waitcnt vmcnt(10)" ::: "memory"); }  // Q1 (V+Q2 out)
    else if (qb == 2) { asm volatile("s_waitcnt vmcnt(2)" ::: "memory"); }   // Q2 (Q3 out)
    else if (qb == 3) { asm volatile("s_waitcnt vmcnt(0)" ::: "memory"); }   // Q3 (+V drained)
    if (qb) { __builtin_amdgcn_s_barrier(); __builtin_amdgcn_sched_barrier(0); }
    const char* qtb = qpr + (qb & 1)*16384;
    f32x4 acc[8][4] = {};
#pragma unroll
    for (int ks = 0; ks < 2; ks++) {
      bf16x8 af[8];
#pragma unroll
      for (int m = 0; m < 8; m++) {
        int q = m*16 + rA;
        af[m] = *(const bf16x8*)(qtb + q*128 + (((ks*4 + g) ^ (q & 7))*16));
      }
      __builtin_amdgcn_s_setprio(1);
#pragma unroll
      for (int m = 0; m < 8; m++)
#pragma unroll
        for (int n = 0; n < 4; n++)
          acc[m][n] = __builtin_amdgcn_mfma_f32_16x16x32_bf16(af[m], kf[n][ks], acc[m][n], 0, 0, 0);
      __builtin_amdgcn_s_setprio(0);
    }
    if (qb < 3) __builtin_amdgcn_s_barrier();   // all waves done reading qtb
    if (qb < 2) STAGE_Q(qb & 1, qb + 2);        // restage freed buffer
#pragma unroll
    for (int m = 0; m < 8; m++)                 // exp2-sum overlaps staging DMA
#pragma unroll
      for (int n = 0; n < 4; n++) {
        float s = 0.f;
#pragma unroll
        for (int r = 0; r < 4; r++) s += ex2(acc[m][n][r]);
        Zacc[n] += s;
      }
  }
#undef STAGE_Q
#pragma unroll
  for (int n = 0; n < 4; n++) {
    float v = Zacc[n];
    v += __shfl_xor(v, 16);
    v += __shfl_xor(v, 32);
    if (lane < 16) ((float*)qpr)[w*64 + n*16 + lane] = 1.0f / v;   // zl handoff in LDS
  }
  __syncthreads();                                // zl visible; V already drained (vmcnt0 above)

  // ---- pass 2: 32x32x16, P in registers; wave owns q in [w*64, w*64+64) ----
  const int l31 = lane & 31, hi5 = lane >> 5;
  bf16x8 qf2[2][4];                               // B-op: q-col = l31, d = ksd*16 + hi5*8
#pragma unroll
  for (int qb = 0; qb < 2; qb++)
#pragma unroll
    for (int ksd = 0; ksd < 4; ksd++)
      qf2[qb][ksd] = *(const bf16x8*)(qbase + (size_t)(w*64 + qb*32 + l31)*512 + ksd*16 + hi5*8);
  const float* zl = (const float*)qpr;
  f32x16 oacc[2][2] = {};
  for (int kc = 0; kc < 16; kc++) {
    bf16x8 kf2[4];                                // A-op: k-row = l31, d = ksd*16 + hi5*8
#pragma unroll
    for (int ksd = 0; ksd < 4; ksd++) {
      int k = kc*32 + l31;
      kf2[ksd] = *(const bf16x8*)(kt + k*128 + (((ksd*2 + hi5) ^ (k & 7))*16));
    }
    bf16x8 vf2[2][2];                             // B-op: d-col = l31, k = hi5*8
#pragma unroll
    for (int db = 0; db < 2; db++)
#pragma unroll
      for (int ks = 0; ks < 2; ks++) {
        int d = db*32 + l31;
        vf2[db][ks] = *(const bf16x8*)(vt + d*1024 + (((kc*4 + ks*2 + hi5) ^ (d & 7))*16));
      }
    f32x4 zv[4];                                  // zinv[k], k uniform per (reg>>2, hi5): broadcast
#pragma unroll
    for (int j = 0; j < 4; j++)
      zv[j] = *(const f32x4*)(zl + kc*32 + j*8 + hi5*4);
#pragma unroll
    for (int qb = 0; qb < 2; qb++) {
      f32x16 s = {};
      __builtin_amdgcn_s_setprio(1);
#pragma unroll
      for (int ksd = 0; ksd < 4; ksd++)
        s = __builtin_amdgcn_mfma_f32_32x32x16_bf16(kf2[ksd], qf2[qb][ksd], s, 0, 0, 0);
      __builtin_amdgcn_s_setprio(0);
      // P[q=l31][k = (r&3) + 8*(r>>2) + 4*hi5 + kc*32] = 2^s * zinv[k]
      float e[16];
#pragma unroll
      for (int r = 0; r < 16; r++) e[r] = ex2(s[r]) * zv[r >> 2][r & 3];
      // assemble PV A-frags: cvt_pk consecutive-k pairs, permlane32_swap fills lane-halves
      uint32_t x0 = cvtpk(e[0], e[1]),   y0 = cvtpk(e[4], e[5]);
      uint32_t x1 = cvtpk(e[2], e[3]),   y1 = cvtpk(e[6], e[7]);
      uint32_t x2 = cvtpk(e[8], e[9]),   y2 = cvtpk(e[12], e[13]);
      uint32_t x3 = cvtpk(e[10], e[11]), y3 = cvtpk(e[14], e[15]);
      uint2v r0 = __builtin_amdgcn_permlane32_swap(x0, y0, false, false);
      uint2v r1 = __builtin_amdgcn_permlane32_swap(x1, y1, false, false);
      uint2v r2 = __builtin_amdgcn_permlane32_swap(x2, y2, false, false);
      uint2v r3 = __builtin_amdgcn_permlane32_swap(x3, y3, false, false);
      union { uint32_t u[4]; bf16x8 v; } p0, p1;
      p0.u[0] = r0[0]; p0.u[1] = r1[0]; p0.u[2] = r0[1]; p0.u[3] = r1[1];  // k 0..15 of chunk
      p1.u[0] = r2[0]; p1.u[1] = r3[0]; p1.u[2] = r2[1]; p1.u[3] = r3[1];  // k 16..31
      __builtin_amdgcn_s_setprio(1);
#pragma unroll
      for (int db = 0; db < 2; db++) {
        oacc[qb][db] = __builtin_amdgcn_mfma_f32_32x32x16_bf16(p0.v, vf2[db][0], oacc[qb][db], 0, 0, 0);
        oacc[qb][db] = __builtin_amdgcn_mfma_f32_32x32x16_bf16(p1.v, vf2[db][1], oacc[qb][db], 0, 0, 0);
      }
      __builtin_amdgcn_s_setprio(0);
    }
  }
#pragma unroll
  for (int qb = 0; qb < 2; qb++)
#pragma unroll
    for (int db = 0; db < 2; db++)
#pragma unroll
      for (int r = 0; r < 16; r++) {
        int q = w*64 + qb*32 + (r & 3) + 8*(r >> 2) + 4*hi5;
        int d = db*32 + l31;
        attn[(size_t)(b*512 + q)*512 + h*64 + d] = f2b(oacc[qb][db][r]);
      }
}

// ---------------- host launcher ----------------
extern "C" void kernel_launch(void* const* d_in, const int* in_sizes, int n_in,
                              void* d_out, int out_size, void* d_ws, size_t ws_size,
                              hipStream_t stream) {
  const float* Q  = (const float*)d_in[0];
  const float* K  = (const float*)d_in[1];
  const float* Wq = (const float*)d_in[2];
  const float* bq = (const float*)d_in[3];
  const float* Wk = (const float*)d_in[4];
  const float* bk = (const float*)d_in[5];
  const float* Wv = (const float*)d_in[6];
  const float* bv = (const float*)d_in[7];
  const float* Wo = (const float*)d_in[8];
  const float* bo = (const float*)d_in[9];
  const float* W1 = (const float*)d_in[10];
  const float* b1 = (const float*)d_in[11];
  const float* W2 = (const float*)d_in[12];
  const float* b2 = (const float*)d_in[13];
  float* out = (float*)d_out;

  const size_t SZ = (size_t)16384 * 512;
  ushort* Qb   = (ushort*)d_ws;                 // later reused as attn
  ushort* Kb   = Qb + SZ;                       // later reused as outb
  ushort* qp   = Kb + SZ;
  ushort* kp   = qp + SZ;
  ushort* vpT  = kp + SZ;                       // v-projection, transposed; later reused as h1
  ushort* Wb   = vpT + SZ;
  float*  zinv = (float*)(Wb + 6 * (size_t)262144);
  ushort* attn = Qb;
  ushort* outb = Kb;
  ushort* h1   = vpT;

  k_cvt<<<dim3(17920), dim3(256), 0, stream>>>(Q, K, Wq, Wk, Wv, Wo, W1, W2, Qb, Kb, Wb);
  k_gemm_qkv<<<dim3(64, 4, 3), dim3(512), 0, stream>>>(Qb, Kb, Wb, bq, bk, bv, qp, vpT);
  k_att2<<<dim3(256), dim3(512), 0, stream>>>(qp, kp, vpT, zinv, attn);
  k_gemm<1><<<dim3(64, 4), dim3(512), 0, stream>>>(attn, Wb + 3*(size_t)262144, bo, Q, out, outb);
  k_gemm<2><<<dim3(64, 4), dim3(512), 0, stream>>>(outb, Wb + 4*(size_t)262144, b1, nullptr, nullptr, h1);
  k_gemm<3><<<dim3(64, 4), dim3(512), 0, stream>>>(h1, Wb + 5*(size_t)262144, b2, nullptr, out, nullptr);
}

// Round 10
// 146.547 us; speedup vs baseline: 1.1254x; 1.0120x over previous
//
#include <hip/hip_runtime.h>
#include <stdint.h>

// MAB block: B=32, N=512, D=512, H=8, dh=64.  M = B*N = 16384.
#define SCALE_ 0.044194173824159216f
// scale * log2(e): folded into the q-projection so attention uses exp2 directly.
#define QSC_ (0.044194173824159216f * 1.4426950408889634f)

typedef __attribute__((ext_vector_type(8))) short bf16x8;
typedef __attribute__((ext_vector_type(4))) float f32x4;
typedef __attribute__((ext_vector_type(16))) float f32x16;
typedef __attribute__((ext_vector_type(2))) unsigned int uint2v;

__device__ __forceinline__ ushort f2b(float f) {
  union { float f; uint32_t u; } v; v.f = f;
  return (ushort)((v.u + 0x7fffu + ((v.u >> 16) & 1u)) >> 16);  // RNE
}
__device__ __forceinline__ uint32_t cvtpk(float lo, float hi) {
  uint32_t r; asm("v_cvt_pk_bf16_f32 %0, %1, %2" : "=v"(r) : "v"(lo), "v"(hi)); return r;
}
__device__ __forceinline__ float ex2(float x) {          // 2^x (v_exp_f32)
  float r; asm("v_exp_f32 %0, %1" : "=v"(r) : "v"(x)); return r;
}
__device__ __forceinline__ void gld16(void* lds, const void* g) {
  __builtin_amdgcn_global_load_lds(
      (const __attribute__((address_space(1))) uint32_t*)g,
      (__attribute__((address_space(3))) uint32_t*)lds, 16, 0, 0);
}

// ---------------- fp32 -> bf16 convert (weights only; Q/K fused into qkv GEMM) ----------------
__global__ __launch_bounds__(256)
void k_cvtw(const float* __restrict__ w0, const float* __restrict__ w1,
            const float* __restrict__ w2, const float* __restrict__ w3,
            const float* __restrict__ w4, const float* __restrict__ w5,
            ushort* __restrict__ Wb)
{
  const int NW = 262144;
  int i = (blockIdx.x * 256 + threadIdx.x) * 4;
  int seg = i >> 18;
  int off = i & (NW - 1);
  const float* src;
  switch (seg) { case 0: src = w0; break; case 1: src = w1; break; case 2: src = w2; break;
                 case 3: src = w3; break; case 4: src = w4; break; default: src = w5; }
  float4 v = *(const float4*)(src + off);
  ushort4 o = make_ushort4(f2b(v.x), f2b(v.y), f2b(v.z), f2b(v.w));
  *(ushort4*)(Wb + (size_t)seg * NW + off) = o;
}

// ---------------- GEMM C = A(bf16,[M,512]) @ Bw(bf16,[512,512])^T ----------------
// 256x128 tile, BK=64, 512 threads (8 waves = 4M x 2N).  Triple-buffered LDS,
// counted vmcnt, 3-bit slot swizzle.  Used by the 3 tail GEMMs (bf16 A via gld_lds).
// EPI: 1 = Q + (acc+bias) -> f32 + bf16   2 = relu->bf16   3 = out += acc+bias
template<int EPI>
__device__ __forceinline__ void gemm_body(const ushort* __restrict__ A, const ushort* __restrict__ Bw,
                                          const float* __restrict__ bias, const float* __restrict__ extra,
                                          float* __restrict__ outf, ushort* __restrict__ outb,
                                          char* lds, int m0, int n0)
{
  const int t = threadIdx.x;           // 0..511
  const int w = t >> 6, lane = t & 63;
  const int wm = w >> 1, wn = w & 1;   // 4M x 2N wave grid
  const int rA = lane & 15, g = lane >> 4;

  const ushort* srcA[4]; int ldsA[4];
#pragma unroll
  for (int j = 0; j < 4; j++) {
    int L = (t + j*512) * 16;
    int U = L ^ (((L >> 7) & 7) << 4);
    srcA[j] = A + (size_t)(m0 + (U >> 7))*512 + ((U & 127) >> 1);
    ldsA[j] = L;
  }
  const ushort* srcB[2]; int ldsB[2];
#pragma unroll
  for (int j = 0; j < 2; j++) {
    int L = (t + j*512) * 16;
    int U = L ^ (((L >> 7) & 7) << 4);
    srcB[j] = Bw + (size_t)(n0 + (U >> 7))*512 + ((U & 127) >> 1);
    ldsB[j] = 32768 + L;
  }

#define STAGE_A(ti) do { char* bb_ = lds + ((ti) % 3) * 49152; \
    _Pragma("unroll") \
    for (int j = 0; j < 4; j++) gld16(bb_ + ldsA[j], srcA[j] + (ti)*64); } while (0)
#define STAGE_B(ti) do { char* bb_ = lds + ((ti) % 3) * 49152; \
    _Pragma("unroll") \
    for (int j = 0; j < 2; j++) gld16(bb_ + ldsB[j], srcB[j] + (ti)*64); } while (0)

  STAGE_A(0); STAGE_B(0);
  STAGE_A(1); STAGE_B(1);

  f32x4 acc[4][4] = {};
  for (int i = 0; i < 8; i++) {
    if (i < 7) asm volatile("s_waitcnt vmcnt(6)" ::: "memory");
    else       asm volatile("s_waitcnt vmcnt(0)" ::: "memory");
    __builtin_amdgcn_s_barrier();
    __builtin_amdgcn_sched_barrier(0);
    const char* bufc = lds + (i % 3) * 49152;

    bf16x8 afA[4], bfA[4], afB[4], bfB[4];
#pragma unroll
    for (int m = 0; m < 4; m++) {
      int row = wm*64 + m*16 + rA;
      afA[m] = *(const bf16x8*)(bufc + ((row*128 + g*16) ^ ((row & 7) << 4)));
      afB[m] = *(const bf16x8*)(bufc + ((row*128 + 64 + g*16) ^ ((row & 7) << 4)));
    }
#pragma unroll
    for (int n = 0; n < 4; n++) {
      int row = wn*64 + n*16 + rA;
      bfA[n] = *(const bf16x8*)(bufc + 32768 + ((row*128 + g*16) ^ ((row & 7) << 4)));
      bfB[n] = *(const bf16x8*)(bufc + 32768 + ((row*128 + 64 + g*16) ^ ((row & 7) << 4)));
    }
    if (i < 6) { STAGE_A(i + 2); STAGE_B(i + 2); }
    __builtin_amdgcn_sched_barrier(0);
    __builtin_amdgcn_s_setprio(1);
#pragma unroll
    for (int m = 0; m < 4; m++)
#pragma unroll
      for (int n = 0; n < 4; n++)
        acc[m][n] = __builtin_amdgcn_mfma_f32_16x16x32_bf16(afA[m], bfA[n], acc[m][n], 0, 0, 0);
#pragma unroll
    for (int m = 0; m < 4; m++)
#pragma unroll
      for (int n = 0; n < 4; n++)
        acc[m][n] = __builtin_amdgcn_mfma_f32_16x16x32_bf16(afB[m], bfB[n], acc[m][n], 0, 0, 0);
    __builtin_amdgcn_s_setprio(0);
  }
#undef STAGE_A
#undef STAGE_B

#pragma unroll
  for (int m = 0; m < 4; m++)
#pragma unroll
    for (int n = 0; n < 4; n++) {
      int col = n0 + wn*64 + n*16 + rA;
      float bb = bias[col];
#pragma unroll
      for (int r = 0; r < 4; r++) {
        int row = m0 + wm*64 + m*16 + g*4 + r;
        size_t idx = (size_t)row*512 + col;
        float v = acc[m][n][r] + bb;
        if (EPI == 1)      { float o = extra[idx] + v; outf[idx] = o; outb[idx] = f2b(o); }
        else if (EPI == 2) outb[idx] = f2b(v > 0.f ? v : 0.f);
        else               outf[idx] += v;
      }
    }
}

template<int EPI>
__global__ __launch_bounds__(512, 2)
void k_gemm(const ushort* __restrict__ A, const ushort* __restrict__ Bw,
            const float* __restrict__ bias, const float* __restrict__ extra,
            float* __restrict__ outf, ushort* __restrict__ outb)
{
  __shared__ __align__(16) char lds[3*49152];   // 144 KB
  gemm_body<EPI>(A, Bw, bias, extra, outf, outb, lds, blockIdx.x*256, blockIdx.y*128);
}

// ---------------- qkv GEMM with fused f32->bf16 A-staging (T14 async-split) ----------------
// A read as f32 (Q or K originals): per tile, 8 coalesced float4 loads issued one iter
// ahead into alternating reg sets; packed via cvt_pk (RNE) + 4 ds_write_b128 into the
// same swizzled LDS layout.  B (weights) stays gld_lds.  Counted vmcnt re-derived for the
// mixed FIFO: queue at top = [SB(i):2, LA(i+1):8, SB(i+1):2] -> vmcnt(10) (2 at i=0, 0 at i=7).
// EPI: 0 = (acc+bias)*os -> bf16    4 = v-projection: write transposed vpT[(b,h,d),k]
template<int EPI>
__device__ __forceinline__ void gemm_f32a_body(const float* __restrict__ A32, const ushort* __restrict__ Bw,
                                               const float* __restrict__ bias,
                                               float* __restrict__ outf, ushort* __restrict__ outb,
                                               char* lds, int m0, int n0, float os)
{
  const int t = threadIdx.x;
  const int w = t >> 6, lane = t & 63;
  const int wm = w >> 1, wn = w & 1;
  const int rA = lane & 15, g = lane >> 4;

  const float* srcA[4]; int ldsA[4];
#pragma unroll
  for (int j = 0; j < 4; j++) {
    int L = (t + j*512) * 16;
    int U = L ^ (((L >> 7) & 7) << 4);
    srcA[j] = A32 + (size_t)(m0 + (U >> 7))*512 + ((U & 127) >> 1);
    ldsA[j] = L;
  }
  const ushort* srcB[2]; int ldsB[2];
#pragma unroll
  for (int j = 0; j < 2; j++) {
    int L = (t + j*512) * 16;
    int U = L ^ (((L >> 7) & 7) << 4);
    srcB[j] = Bw + (size_t)(n0 + (U >> 7))*512 + ((U & 127) >> 1);
    ldsB[j] = 32768 + L;
  }

#define QLA(ti, R) do { \
    _Pragma("unroll") \
    for (int j = 0; j < 4; j++) { \
      R[2*j]   = *(const float4*)(srcA[j] + (ti)*64); \
      R[2*j+1] = *(const float4*)(srcA[j] + (ti)*64 + 4); } } while (0)
#define QWA(ti, R) do { char* bb_ = lds + ((ti) % 3) * 49152; \
    _Pragma("unroll") \
    for (int j = 0; j < 4; j++) { \
      uint4 qq; \
      qq.x = cvtpk(R[2*j].x,   R[2*j].y); \
      qq.y = cvtpk(R[2*j].z,   R[2*j].w); \
      qq.z = cvtpk(R[2*j+1].x, R[2*j+1].y); \
      qq.w = cvtpk(R[2*j+1].z, R[2*j+1].w); \
      *(uint4*)(bb_ + ldsA[j]) = qq; } } while (0)
#define QSB(ti) do { char* bb_ = lds + ((ti) % 3) * 49152; \
    _Pragma("unroll") \
    for (int j = 0; j < 2; j++) gld16(bb_ + ldsB[j], srcB[j] + (ti)*64); } while (0)

  float4 a0[8], a1[8];
  QLA(0, a0);
  __builtin_amdgcn_sched_barrier(0);
  QLA(1, a1);
  __builtin_amdgcn_sched_barrier(0);
  QSB(0); QSB(1);
  __builtin_amdgcn_sched_barrier(0);
  asm volatile("s_waitcnt vmcnt(12)" ::: "memory");   // LA(0) landed
  QWA(0, a0);

  f32x4 acc[4][4] = {};

#define QITER(i, RI, RW) do { \
    if ((i) == 0)      asm volatile("s_waitcnt vmcnt(2) lgkmcnt(0)" ::: "memory"); \
    else if ((i) == 7) asm volatile("s_waitcnt vmcnt(0) lgkmcnt(0)" ::: "memory"); \
    else               asm volatile("s_waitcnt vmcnt(10) lgkmcnt(0)" ::: "memory"); \
    __builtin_amdgcn_s_barrier(); \
    __builtin_amdgcn_sched_barrier(0); \
    const char* bufc = lds + ((i) % 3) * 49152; \
    bf16x8 afA[4], bfA[4], afB[4], bfB[4]; \
    _Pragma("unroll") \
    for (int m = 0; m < 4; m++) { \
      int row = wm*64 + m*16 + rA; \
      afA[m] = *(const bf16x8*)(bufc + ((row*128 + g*16) ^ ((row & 7) << 4))); \
      afB[m] = *(const bf16x8*)(bufc + ((row*128 + 64 + g*16) ^ ((row & 7) << 4))); \
    } \
    _Pragma("unroll") \
    for (int n = 0; n < 4; n++) { \
      int row = wn*64 + n*16 + rA; \
      bfA[n] = *(const bf16x8*)(bufc + 32768 + ((row*128 + g*16) ^ ((row & 7) << 4))); \
      bfB[n] = *(const bf16x8*)(bufc + 32768 + ((row*128 + 64 + g*16) ^ ((row & 7) << 4))); \
    } \
    if ((i) < 6) QLA((i) + 2, RI); \
    __builtin_amdgcn_sched_barrier(0); \
    if ((i) < 7) QWA((i) + 1, RW); \
    if ((i) < 6) QSB((i) + 2); \
    __builtin_amdgcn_sched_barrier(0); \
    __builtin_amdgcn_s_setprio(1); \
    _Pragma("unroll") \
    for (int m = 0; m < 4; m++) \
      _Pragma("unroll") \
      for (int n = 0; n < 4; n++) \
        acc[m][n] = __builtin_amdgcn_mfma_f32_16x16x32_bf16(afA[m], bfA[n], acc[m][n], 0, 0, 0); \
    _Pragma("unroll") \
    for (int m = 0; m < 4; m++) \
      _Pragma("unroll") \
      for (int n = 0; n < 4; n++) \
        acc[m][n] = __builtin_amdgcn_mfma_f32_16x16x32_bf16(afB[m], bfB[n], acc[m][n], 0, 0, 0); \
    __builtin_amdgcn_s_setprio(0); \
  } while (0)

  QITER(0, a0, a1);
  QITER(1, a1, a0);
  QITER(2, a0, a1);
  QITER(3, a1, a0);
  QITER(4, a0, a1);
  QITER(5, a1, a0);
  QITER(6, a0, a1);
  QITER(7, a1, a0);
#undef QITER
#undef QLA
#undef QWA
#undef QSB

#pragma unroll
  for (int m = 0; m < 4; m++)
#pragma unroll
    for (int n = 0; n < 4; n++) {
      int col = n0 + wn*64 + n*16 + rA;
      float bb = bias[col];
      if (EPI == 4) {
        int b = m0 >> 9, k0 = m0 & 511;
        int hh = col >> 6, dl = col & 63;
        int kg = k0 + wm*64 + m*16 + g*4;
        float v0 = acc[m][n][0] + bb, v1 = acc[m][n][1] + bb;
        float v2 = acc[m][n][2] + bb, v3 = acc[m][n][3] + bb;
        uint2 pk;
        pk.x = (uint32_t)f2b(v0) | ((uint32_t)f2b(v1) << 16);
        pk.y = (uint32_t)f2b(v2) | ((uint32_t)f2b(v3) << 16);
        *(uint2*)(outb + ((size_t)((b*8 + hh)*64 + dl)*512 + kg)) = pk;
      } else {
#pragma unroll
        for (int r = 0; r < 4; r++) {
          int row = m0 + wm*64 + m*16 + g*4 + r;
          size_t idx = (size_t)row*512 + col;
          outb[idx] = f2b((acc[m][n][r] + bb) * os);
        }
      }
    }
}

__global__ __launch_bounds__(512, 2)
void k_gemm_qkvf(const float* __restrict__ Qf, const float* __restrict__ Kf,
                 const ushort* __restrict__ Wb, const float* __restrict__ bq,
                 const float* __restrict__ bk, const float* __restrict__ bvv,
                 ushort* __restrict__ qkout, ushort* __restrict__ vpT)
{
  __shared__ __align__(16) char lds[3*49152];
  int z = blockIdx.z;
  if (z == 2) {
    gemm_f32a_body<4>(Kf, Wb + 2*(size_t)262144, bvv, nullptr, vpT,
                      lds, blockIdx.x*256, blockIdx.y*128, 1.0f);
  } else if (z == 1) {
    gemm_f32a_body<0>(Kf, Wb + (size_t)262144, bk, nullptr, qkout + (size_t)8388608,
                      lds, blockIdx.x*256, blockIdx.y*128, 1.0f);
  } else {
    gemm_f32a_body<0>(Qf, Wb, bq, nullptr, qkout,
                      lds, blockIdx.x*256, blockIdx.y*128, QSC_);
  }
}

// ---------------- fused attention: zinv (pass1, 16x16) + PV (pass2, 32x32 in-register P) ----------------
__global__ __launch_bounds__(512, 2)
void k_att2(const ushort* __restrict__ qp, const ushort* __restrict__ kp,
            const ushort* __restrict__ vpT, float* __restrict__ zinv,
            ushort* __restrict__ attn)
{
  __shared__ __align__(16) char kt[65536];
  __shared__ __align__(16) char vt[65536];
  __shared__ __align__(16) char qpr[32768];
  int bh = blockIdx.x;
  int b = bh >> 3, h = bh & 7;
  int t = threadIdx.x, w = t >> 6, lane = t & 63;
  int rA = lane & 15, g = lane >> 4;
  const ushort* kbase = kp + (size_t)(b*512)*512 + h*64;
  const ushort* qbase = qp + (size_t)(b*512)*512 + h*64;
  const ushort* vbase = vpT + (size_t)bh*64*512;

  // ---- issue all stages: K(8/thread), Q0(2), Q1(2), V(8) ----
#pragma unroll
  for (int i = 0; i < 8; i++) {          // K: [512][64] swizzled slot^(k&7)
    int c = i*512 + t; int row = c >> 3, sl = c & 7;
    gld16(kt + c*16, kbase + (size_t)row*512 + ((sl ^ (row & 7))*8));
  }
#define STAGE_Q(buf, qb) do { \
    _Pragma("unroll") \
    for (int i = 0; i < 2; i++) { \
      int c = i*512 + t; int row = c >> 3, sl = c & 7; \
      gld16(qpr + (buf)*16384 + c*16, \
            qbase + (size_t)((qb)*128 + row)*512 + ((sl ^ (row & 7))*8)); } } while (0)
  STAGE_Q(0, 0);
  STAGE_Q(1, 1);
#pragma unroll
  for (int i = 0; i < 8; i++) {          // V: [64][512] swizzled slot low3 ^ (d&7)
    int c = i*512 + t; int d = c >> 6, sl = c & 63;
    gld16(vt + c*16, vbase + (size_t)d*512 + ((sl ^ (d & 7))*8));
  }

  // ---- pass 1: zl[k] = 1/sum_q 2^s; wave owns k in [w*64, w*64+64) ----
  asm volatile("s_waitcnt vmcnt(10)" ::: "memory");   // K + Q0 landed (Q1,V in flight)
  __builtin_amdgcn_s_barrier();
  __builtin_amdgcn_sched_barrier(0);
  bf16x8 kf[4][2];
#pragma unroll
  for (int n = 0; n < 4; n++)
#pragma unroll
    for (int ks = 0; ks < 2; ks++) {
      int k = w*64 + n*16 + rA;
      kf[n][ks] = *(const bf16x8*)(kt + k*128 + (((ks*4 + g) ^ (k & 7))*16));
    }
  float Zacc[4] = {0.f, 0.f, 0.f, 0.f};
  for (int qb = 0; qb < 4; qb++) {
    if (qb == 1)      { asm volatile("s_waitcnt vmcnt(10)" ::: "memory"); }  // Q1 (V+Q2 out)
    else if (qb == 2) { asm volatile("s_waitcnt vmcnt(2)" ::: "memory"); }   // Q2 (Q3 out)
    else if (qb == 3) { asm volatile("s_waitcnt vmcnt(0)" ::: "memory"); }   // Q3 (+V drained)
    if (qb) { __builtin_amdgcn_s_barrier(); __builtin_amdgcn_sched_barrier(0); }
    const char* qtb = qpr + (qb & 1)*16384;
    f32x4 acc[8][4] = {};
#pragma unroll
    for (int ks = 0; ks < 2; ks++) {
      bf16x8 af[8];
#pragma unroll
      for (int m = 0; m < 8; m++) {
        int q = m*16 + rA;
        af[m] = *(const bf16x8*)(qtb + q*128 + (((ks*4 + g) ^ (q & 7))*16));
      }
      __builtin_amdgcn_s_setprio(1);
#pragma unroll
      for (int m = 0; m < 8; m++)
#pragma unroll
        for (int n = 0; n < 4; n++)
          acc[m][n] = __builtin_amdgcn_mfma_f32_16x16x32_bf16(af[m], kf[n][ks], acc[m][n], 0, 0, 0);
      __builtin_amdgcn_s_setprio(0);
    }
    if (qb < 3) __builtin_amdgcn_s_barrier();   // all waves done reading qtb
    if (qb < 2) STAGE_Q(qb & 1, qb + 2);        // restage freed buffer
#pragma unroll
    for (int m = 0; m < 8; m++)                 // exp2-sum overlaps staging DMA
#pragma unroll
      for (int n = 0; n < 4; n++) {
        float s = 0.f;
#pragma unroll
        for (int r = 0; r < 4; r++) s += ex2(acc[m][n][r]);
        Zacc[n] += s;
      }
  }
#undef STAGE_Q
#pragma unroll
  for (int n = 0; n < 4; n++) {
    float v = Zacc[n];
    v += __shfl_xor(v, 16);
    v += __shfl_xor(v, 32);
    if (lane < 16) ((float*)qpr)[w*64 + n*16 + lane] = 1.0f / v;   // zl handoff in LDS
  }
  __syncthreads();                                // zl visible; V already drained (vmcnt0 above)

  // ---- pass 2: 32x32x16, P in registers; wave owns q in [w*64, w*64+64) ----
  const int l31 = lane & 31, hi5 = lane >> 5;
  bf16x8 qf2[2][4];                               // B-op: q-col = l31, d = ksd*16 + hi5*8
#pragma unroll
  for (int qb = 0; qb < 2; qb++)
#pragma unroll
    for (int ksd = 0; ksd < 4; ksd++)
      qf2[qb][ksd] = *(const bf16x8*)(qbase + (size_t)(w*64 + qb*32 + l31)*512 + ksd*16 + hi5*8);
  const float* zl = (const float*)qpr;
  f32x16 oacc[2][2] = {};
  for (int kc = 0; kc < 16; kc++) {
    bf16x8 kf2[4];                                // A-op: k-row = l31, d = ksd*16 + hi5*8
#pragma unroll
    for (int ksd = 0; ksd < 4; ksd++) {
      int k = kc*32 + l31;
      kf2[ksd] = *(const bf16x8*)(kt + k*128 + (((ksd*2 + hi5) ^ (k & 7))*16));
    }
    bf16x8 vf2[2][2];                             // B-op: d-col = l31, k = hi5*8
#pragma unroll
    for (int db = 0; db < 2; db++)
#pragma unroll
      for (int ks = 0; ks < 2; ks++) {
        int d = db*32 + l31;
        vf2[db][ks] = *(const bf16x8*)(vt + d*1024 + (((kc*4 + ks*2 + hi5) ^ (d & 7))*16));
      }
    f32x4 zv[4];                                  // zinv[k], k uniform per (reg>>2, hi5): broadcast
#pragma unroll
    for (int j = 0; j < 4; j++)
      zv[j] = *(const f32x4*)(zl + kc*32 + j*8 + hi5*4);
#pragma unroll
    for (int qb = 0; qb < 2; qb++) {
      f32x16 s = {};
      __builtin_amdgcn_s_setprio(1);
#pragma unroll
      for (int ksd = 0; ksd < 4; ksd++)
        s = __builtin_amdgcn_mfma_f32_32x32x16_bf16(kf2[ksd], qf2[qb][ksd], s, 0, 0, 0);
      __builtin_amdgcn_s_setprio(0);
      // P[q=l31][k = (r&3) + 8*(r>>2) + 4*hi5 + kc*32] = 2^s * zinv[k]
      float e[16];
#pragma unroll
      for (int r = 0; r < 16; r++) e[r] = ex2(s[r]) * zv[r >> 2][r & 3];
      // assemble PV A-frags: cvt_pk consecutive-k pairs, permlane32_swap fills lane-halves
      uint32_t x0 = cvtpk(e[0], e[1]),   y0 = cvtpk(e[4], e[5]);
      uint32_t x1 = cvtpk(e[2], e[3]),   y1 = cvtpk(e[6], e[7]);
      uint32_t x2 = cvtpk(e[8], e[9]),   y2 = cvtpk(e[12], e[13]);
      uint32_t x3 = cvtpk(e[10], e[11]), y3 = cvtpk(e[14], e[15]);
      uint2v r0 = __builtin_amdgcn_permlane32_swap(x0, y0, false, false);
      uint2v r1 = __builtin_amdgcn_permlane32_swap(x1, y1, false, false);
      uint2v r2 = __builtin_amdgcn_permlane32_swap(x2, y2, false, false);
      uint2v r3 = __builtin_amdgcn_permlane32_swap(x3, y3, false, false);
      union { uint32_t u[4]; bf16x8 v; } p0, p1;
      p0.u[0] = r0[0]; p0.u[1] = r1[0]; p0.u[2] = r0[1]; p0.u[3] = r1[1];  // k 0..15 of chunk
      p1.u[0] = r2[0]; p1.u[1] = r3[0]; p1.u[2] = r2[1]; p1.u[3] = r3[1];  // k 16..31
      __builtin_amdgcn_s_setprio(1);
#pragma unroll
      for (int db = 0; db < 2; db++) {
        oacc[qb][db] = __builtin_amdgcn_mfma_f32_32x32x16_bf16(p0.v, vf2[db][0], oacc[qb][db], 0, 0, 0);
        oacc[qb][db] = __builtin_amdgcn_mfma_f32_32x32x16_bf16(p1.v, vf2[db][1], oacc[qb][db], 0, 0, 0);
      }
      __builtin_amdgcn_s_setprio(0);
    }
  }
#pragma unroll
  for (int qb = 0; qb < 2; qb++)
#pragma unroll
    for (int db = 0; db < 2; db++)
#pragma unroll
      for (int r = 0; r < 16; r++) {
        int q = w*64 + qb*32 + (r & 3) + 8*(r >> 2) + 4*hi5;
        int d = db*32 + l31;
        attn[(size_t)(b*512 + q)*512 + h*64 + d] = f2b(oacc[qb][db][r]);
      }
}

// ---------------- host launcher ----------------
extern "C" void kernel_launch(void* const* d_in, const int* in_sizes, int n_in,
                              void* d_out, int out_size, void* d_ws, size_t ws_size,
                              hipStream_t stream) {
  const float* Q  = (const float*)d_in[0];
  const float* K  = (const float*)d_in[1];
  const float* Wq = (const float*)d_in[2];
  const float* bq = (const float*)d_in[3];
  const float* Wk = (const float*)d_in[4];
  const float* bk = (const float*)d_in[5];
  const float* Wv = (const float*)d_in[6];
  const float* bv = (const float*)d_in[7];
  const float* Wo = (const float*)d_in[8];
  const float* bo = (const float*)d_in[9];
  const float* W1 = (const float*)d_in[10];
  const float* b1 = (const float*)d_in[11];
  const float* W2 = (const float*)d_in[12];
  const float* b2 = (const float*)d_in[13];
  float* out = (float*)d_out;

  const size_t SZ = (size_t)16384 * 512;
  ushort* attn = (ushort*)d_ws;                 // slot 0
  ushort* outb = attn + SZ;                     // slot 1
  ushort* qp   = outb + SZ;
  ushort* kp   = qp + SZ;
  ushort* vpT  = kp + SZ;                       // v-projection, transposed; later reused as h1
  ushort* Wb   = vpT + SZ;
  float*  zinv = (float*)(Wb + 6 * (size_t)262144);
  ushort* h1   = vpT;

  k_cvtw<<<dim3(1536), dim3(256), 0, stream>>>(Wq, Wk, Wv, Wo, W1, W2, Wb);
  k_gemm_qkvf<<<dim3(64, 4, 3), dim3(512), 0, stream>>>(Q, K, Wb, bq, bk, bv, qp, vpT);
  k_att2<<<dim3(256), dim3(512), 0, stream>>>(qp, kp, vpT, zinv, attn);
  k_gemm<1><<<dim3(64, 4), dim3(512), 0, stream>>>(attn, Wb + 3*(size_t)262144, bo, Q, out, outb);
  k_gemm<2><<<dim3(64, 4), dim3(512), 0, stream>>>(outb, Wb + 4*(size_t)262144, b1, nullptr, nullptr, h1);
  k_gemm<3><<<dim3(64, 4), dim3(512), 0, stream>>>(h1, Wb + 5*(size_t)262144, b2, nullptr, out, nullptr);
}

// Round 11
// 146.470 us; speedup vs baseline: 1.1260x; 1.0005x over previous
//
#include <hip/hip_runtime.h>
#include <stdint.h>

// MAB block: B=32, N=512, D=512, H=8, dh=64.  M = B*N = 16384.
#define SCALE_ 0.044194173824159216f
// scale * log2(e): folded into the q-projection so attention uses exp2 directly.
#define QSC_ (0.044194173824159216f * 1.4426950408889634f)

typedef __attribute__((ext_vector_type(8))) short bf16x8;
typedef __attribute__((ext_vector_type(4))) float f32x4;
typedef __attribute__((ext_vector_type(16))) float f32x16;
typedef __attribute__((ext_vector_type(2))) unsigned int uint2v;

__device__ __forceinline__ ushort f2b(float f) {
  union { float f; uint32_t u; } v; v.f = f;
  return (ushort)((v.u + 0x7fffu + ((v.u >> 16) & 1u)) >> 16);  // RNE
}
__device__ __forceinline__ uint32_t cvtpk(float lo, float hi) {
  uint32_t r; asm("v_cvt_pk_bf16_f32 %0, %1, %2" : "=v"(r) : "v"(lo), "v"(hi)); return r;
}
__device__ __forceinline__ float ex2(float x) {          // 2^x (v_exp_f32)
  float r; asm("v_exp_f32 %0, %1" : "=v"(r) : "v"(x)); return r;
}
__device__ __forceinline__ void gld16(void* lds, const void* g) {
  __builtin_amdgcn_global_load_lds(
      (const __attribute__((address_space(1))) uint32_t*)g,
      (__attribute__((address_space(3))) uint32_t*)lds, 16, 0, 0);
}

// ---------------- fp32 -> bf16 convert (weights only; Q/K fused into qkv GEMM) ----------------
__global__ __launch_bounds__(256)
void k_cvtw(const float* __restrict__ w0, const float* __restrict__ w1,
            const float* __restrict__ w2, const float* __restrict__ w3,
            const float* __restrict__ w4, const float* __restrict__ w5,
            ushort* __restrict__ Wb)
{
  const int NW = 262144;
  int i = (blockIdx.x * 256 + threadIdx.x) * 4;
  int seg = i >> 18;
  int off = i & (NW - 1);
  const float* src;
  switch (seg) { case 0: src = w0; break; case 1: src = w1; break; case 2: src = w2; break;
                 case 3: src = w3; break; case 4: src = w4; break; default: src = w5; }
  float4 v = *(const float4*)(src + off);
  ushort4 o = make_ushort4(f2b(v.x), f2b(v.y), f2b(v.z), f2b(v.w));
  *(ushort4*)(Wb + (size_t)seg * NW + off) = o;
}

// ---------------- GEMM C = A(bf16,[M,512]) @ Bw(bf16,[512,512])^T ----------------
// 256x128 tile, BK=64, 512 threads (8 waves = 4M x 2N).  Triple-buffered LDS,
// counted vmcnt, 3-bit slot swizzle.  Used by the 3 tail GEMMs (bf16 A via gld_lds).
// EPI: 1 = Q + (acc+bias) -> f32 + bf16   2 = relu->bf16   3 = out += acc+bias
template<int EPI>
__device__ __forceinline__ void gemm_body(const ushort* __restrict__ A, const ushort* __restrict__ Bw,
                                          const float* __restrict__ bias, const float* __restrict__ extra,
                                          float* __restrict__ outf, ushort* __restrict__ outb,
                                          char* lds, int m0, int n0)
{
  const int t = threadIdx.x;           // 0..511
  const int w = t >> 6, lane = t & 63;
  const int wm = w >> 1, wn = w & 1;   // 4M x 2N wave grid
  const int rA = lane & 15, g = lane >> 4;

  const ushort* srcA[4]; int ldsA[4];
#pragma unroll
  for (int j = 0; j < 4; j++) {
    int L = (t + j*512) * 16;
    int U = L ^ (((L >> 7) & 7) << 4);
    srcA[j] = A + (size_t)(m0 + (U >> 7))*512 + ((U & 127) >> 1);
    ldsA[j] = L;
  }
  const ushort* srcB[2]; int ldsB[2];
#pragma unroll
  for (int j = 0; j < 2; j++) {
    int L = (t + j*512) * 16;
    int U = L ^ (((L >> 7) & 7) << 4);
    srcB[j] = Bw + (size_t)(n0 + (U >> 7))*512 + ((U & 127) >> 1);
    ldsB[j] = 32768 + L;
  }

#define STAGE_A(ti) do { char* bb_ = lds + ((ti) % 3) * 49152; \
    _Pragma("unroll") \
    for (int j = 0; j < 4; j++) gld16(bb_ + ldsA[j], srcA[j] + (ti)*64); } while (0)
#define STAGE_B(ti) do { char* bb_ = lds + ((ti) % 3) * 49152; \
    _Pragma("unroll") \
    for (int j = 0; j < 2; j++) gld16(bb_ + ldsB[j], srcB[j] + (ti)*64); } while (0)

  STAGE_A(0); STAGE_B(0);
  STAGE_A(1); STAGE_B(1);

  f32x4 acc[4][4] = {};
  for (int i = 0; i < 8; i++) {
    if (i < 7) asm volatile("s_waitcnt vmcnt(6)" ::: "memory");
    else       asm volatile("s_waitcnt vmcnt(0)" ::: "memory");
    __builtin_amdgcn_s_barrier();
    __builtin_amdgcn_sched_barrier(0);
    const char* bufc = lds + (i % 3) * 49152;

    bf16x8 afA[4], bfA[4], afB[4], bfB[4];
#pragma unroll
    for (int m = 0; m < 4; m++) {
      int row = wm*64 + m*16 + rA;
      afA[m] = *(const bf16x8*)(bufc + ((row*128 + g*16) ^ ((row & 7) << 4)));
      afB[m] = *(const bf16x8*)(bufc + ((row*128 + 64 + g*16) ^ ((row & 7) << 4)));
    }
#pragma unroll
    for (int n = 0; n < 4; n++) {
      int row = wn*64 + n*16 + rA;
      bfA[n] = *(const bf16x8*)(bufc + 32768 + ((row*128 + g*16) ^ ((row & 7) << 4)));
      bfB[n] = *(const bf16x8*)(bufc + 32768 + ((row*128 + 64 + g*16) ^ ((row & 7) << 4)));
    }
    if (i < 6) { STAGE_A(i + 2); STAGE_B(i + 2); }
    __builtin_amdgcn_sched_barrier(0);
    __builtin_amdgcn_s_setprio(1);
#pragma unroll
    for (int m = 0; m < 4; m++)
#pragma unroll
      for (int n = 0; n < 4; n++)
        acc[m][n] = __builtin_amdgcn_mfma_f32_16x16x32_bf16(afA[m], bfA[n], acc[m][n], 0, 0, 0);
#pragma unroll
    for (int m = 0; m < 4; m++)
#pragma unroll
      for (int n = 0; n < 4; n++)
        acc[m][n] = __builtin_amdgcn_mfma_f32_16x16x32_bf16(afB[m], bfB[n], acc[m][n], 0, 0, 0);
    __builtin_amdgcn_s_setprio(0);
  }
#undef STAGE_A
#undef STAGE_B

#pragma unroll
  for (int m = 0; m < 4; m++)
#pragma unroll
    for (int n = 0; n < 4; n++) {
      int col = n0 + wn*64 + n*16 + rA;
      float bb = bias[col];
#pragma unroll
      for (int r = 0; r < 4; r++) {
        int row = m0 + wm*64 + m*16 + g*4 + r;
        size_t idx = (size_t)row*512 + col;
        float v = acc[m][n][r] + bb;
        if (EPI == 1)      { float o = extra[idx] + v; outf[idx] = o; outb[idx] = f2b(o); }
        else if (EPI == 2) outb[idx] = f2b(v > 0.f ? v : 0.f);
        else               outf[idx] += v;
      }
    }
}

template<int EPI>
__global__ __launch_bounds__(512, 2)
void k_gemm(const ushort* __restrict__ A, const ushort* __restrict__ Bw,
            const float* __restrict__ bias, const float* __restrict__ extra,
            float* __restrict__ outf, ushort* __restrict__ outb)
{
  __shared__ __align__(16) char lds[3*49152];   // 144 KB
  gemm_body<EPI>(A, Bw, bias, extra, outf, outb, lds, blockIdx.x*256, blockIdx.y*128);
}

// ---------------- qkv GEMM with fused f32->bf16 A-staging, 3-deep reg pipeline ----------------
// A read as f32 (Q or K originals): QLA(i+3) gives every load TWO full iterations of
// latency budget before QWA(i+1) packs it (cvt_pk RNE) into swizzled LDS.  B stays gld_lds.
// Steady-state FIFO at top of iter i: [LA(i+2):8, SB(i+1):2, LA(i+3):8, SB(i+2):2] = 20;
// vmcnt(10) waits SB(i+1)... (shifted by one: waits SB(i), drains LA(i+2)) — see derivation.
// EPI: 0 = (acc+bias)*os -> bf16    4 = v-projection: write transposed vpT[(b,h,d),k]
template<int EPI>
__device__ __forceinline__ void gemm_f32a_body(const float* __restrict__ A32, const ushort* __restrict__ Bw,
                                               const float* __restrict__ bias,
                                               float* __restrict__ outf, ushort* __restrict__ outb,
                                               char* lds, int m0, int n0, float os)
{
  const int t = threadIdx.x;
  const int w = t >> 6, lane = t & 63;
  const int wm = w >> 1, wn = w & 1;
  const int rA = lane & 15, g = lane >> 4;

  const float* srcA[4]; int ldsA[4];
#pragma unroll
  for (int j = 0; j < 4; j++) {
    int L = (t + j*512) * 16;
    int U = L ^ (((L >> 7) & 7) << 4);
    srcA[j] = A32 + (size_t)(m0 + (U >> 7))*512 + ((U & 127) >> 1);
    ldsA[j] = L;
  }
  const ushort* srcB[2]; int ldsB[2];
#pragma unroll
  for (int j = 0; j < 2; j++) {
    int L = (t + j*512) * 16;
    int U = L ^ (((L >> 7) & 7) << 4);
    srcB[j] = Bw + (size_t)(n0 + (U >> 7))*512 + ((U & 127) >> 1);
    ldsB[j] = 32768 + L;
  }

#define QLA(ti, R) do { \
    _Pragma("unroll") \
    for (int j = 0; j < 4; j++) { \
      R[2*j]   = *(const float4*)(srcA[j] + (ti)*64); \
      R[2*j+1] = *(const float4*)(srcA[j] + (ti)*64 + 4); } } while (0)
#define QWA(ti, R) do { char* bb_ = lds + ((ti) % 3) * 49152; \
    _Pragma("unroll") \
    for (int j = 0; j < 4; j++) { \
      uint4 qq; \
      qq.x = cvtpk(R[2*j].x,   R[2*j].y); \
      qq.y = cvtpk(R[2*j].z,   R[2*j].w); \
      qq.z = cvtpk(R[2*j+1].x, R[2*j+1].y); \
      qq.w = cvtpk(R[2*j+1].z, R[2*j+1].w); \
      *(uint4*)(bb_ + ldsA[j]) = qq; } } while (0)
#define QSB(ti) do { char* bb_ = lds + ((ti) % 3) * 49152; \
    _Pragma("unroll") \
    for (int j = 0; j < 2; j++) gld16(bb_ + ldsB[j], srcB[j] + (ti)*64); } while (0)

  float4 a0[8], a1[8], a2[8];
  // prologue: FIFO = [SB0:2, LA0:8, LA1:8, LA2:8, SB1:2]
  QSB(0);
  QLA(0, a0);
  QLA(1, a1);
  QLA(2, a2);
  QSB(1);
  __builtin_amdgcn_sched_barrier(0);
  asm volatile("s_waitcnt vmcnt(18)" ::: "memory");   // LA0 (and SB0) done
  QWA(0, a0);

  f32x4 acc[4][4] = {};

  // steady iter i: top vmcnt(10) waits SB(i) and drains LA(i+1) (2-iter-old) -> QWA(i+1) free.
#define QITER(i, RW, RL) do { \
    if ((i) <= 5)      asm volatile("s_waitcnt vmcnt(10) lgkmcnt(0)" ::: "memory"); \
    else if ((i) == 6) asm volatile("s_waitcnt vmcnt(2) lgkmcnt(0)" ::: "memory"); \
    else               asm volatile("s_waitcnt vmcnt(0) lgkmcnt(0)" ::: "memory"); \
    __builtin_amdgcn_s_barrier(); \
    __builtin_amdgcn_sched_barrier(0); \
    if ((i) < 7) QWA((i) + 1, RW); \
    __builtin_amdgcn_sched_barrier(0); \
    const char* bufc = lds + ((i) % 3) * 49152; \
    bf16x8 afA[4], bfA[4]; \
    _Pragma("unroll") \
    for (int m = 0; m < 4; m++) { \
      int row = wm*64 + m*16 + rA; \
      afA[m] = *(const bf16x8*)(bufc + ((row*128 + g*16) ^ ((row & 7) << 4))); \
    } \
    _Pragma("unroll") \
    for (int n = 0; n < 4; n++) { \
      int row = wn*64 + n*16 + rA; \
      bfA[n] = *(const bf16x8*)(bufc + 32768 + ((row*128 + g*16) ^ ((row & 7) << 4))); \
    } \
    if ((i) < 5) QLA((i) + 3, RL); \
    if ((i) < 6) QSB((i) + 2); \
    __builtin_amdgcn_sched_barrier(0); \
    __builtin_amdgcn_s_setprio(1); \
    _Pragma("unroll") \
    for (int m = 0; m < 4; m++) \
      _Pragma("unroll") \
      for (int n = 0; n < 4; n++) \
        acc[m][n] = __builtin_amdgcn_mfma_f32_16x16x32_bf16(afA[m], bfA[n], acc[m][n], 0, 0, 0); \
    __builtin_amdgcn_s_setprio(0); \
    bf16x8 afB[4], bfB[4]; \
    _Pragma("unroll") \
    for (int m = 0; m < 4; m++) { \
      int row = wm*64 + m*16 + rA; \
      afB[m] = *(const bf16x8*)(bufc + ((row*128 + 64 + g*16) ^ ((row & 7) << 4))); \
    } \
    _Pragma("unroll") \
    for (int n = 0; n < 4; n++) { \
      int row = wn*64 + n*16 + rA; \
      bfB[n] = *(const bf16x8*)(bufc + 32768 + ((row*128 + 64 + g*16) ^ ((row & 7) << 4))); \
    } \
    __builtin_amdgcn_s_setprio(1); \
    _Pragma("unroll") \
    for (int m = 0; m < 4; m++) \
      _Pragma("unroll") \
      for (int n = 0; n < 4; n++) \
        acc[m][n] = __builtin_amdgcn_mfma_f32_16x16x32_bf16(afB[m], bfB[n], acc[m][n], 0, 0, 0); \
    __builtin_amdgcn_s_setprio(0); \
  } while (0)

  // RW = regs for QWA(i+1) = a[(i+1)%3]; RL = regs for QLA(i+3) = a[(i+3)%3] = a[i%3]
  QITER(0, a1, a0);
  QITER(1, a2, a1);
  QITER(2, a0, a2);
  QITER(3, a1, a0);
  QITER(4, a2, a1);
  QITER(5, a0, a2);
  QITER(6, a1, a0);
  QITER(7, a2, a1);
#undef QITER
#undef QLA
#undef QWA
#undef QSB

#pragma unroll
  for (int m = 0; m < 4; m++)
#pragma unroll
    for (int n = 0; n < 4; n++) {
      int col = n0 + wn*64 + n*16 + rA;
      float bb = bias[col];
      if (EPI == 4) {
        int b = m0 >> 9, k0 = m0 & 511;
        int hh = col >> 6, dl = col & 63;
        int kg = k0 + wm*64 + m*16 + g*4;
        float v0 = acc[m][n][0] + bb, v1 = acc[m][n][1] + bb;
        float v2 = acc[m][n][2] + bb, v3 = acc[m][n][3] + bb;
        uint2 pk;
        pk.x = (uint32_t)f2b(v0) | ((uint32_t)f2b(v1) << 16);
        pk.y = (uint32_t)f2b(v2) | ((uint32_t)f2b(v3) << 16);
        *(uint2*)(outb + ((size_t)((b*8 + hh)*64 + dl)*512 + kg)) = pk;
      } else {
#pragma unroll
        for (int r = 0; r < 4; r++) {
          int row = m0 + wm*64 + m*16 + g*4 + r;
          size_t idx = (size_t)row*512 + col;
          outb[idx] = f2b((acc[m][n][r] + bb) * os);
        }
      }
    }
}

__global__ __launch_bounds__(512, 2)
void k_gemm_qkvf(const float* __restrict__ Qf, const float* __restrict__ Kf,
                 const ushort* __restrict__ Wb, const float* __restrict__ bq,
                 const float* __restrict__ bk, const float* __restrict__ bvv,
                 ushort* __restrict__ qkout, ushort* __restrict__ vpT)
{
  __shared__ __align__(16) char lds[3*49152];
  int z = blockIdx.z;
  if (z == 2) {
    gemm_f32a_body<4>(Kf, Wb + 2*(size_t)262144, bvv, nullptr, vpT,
                      lds, blockIdx.x*256, blockIdx.y*128, 1.0f);
  } else if (z == 1) {
    gemm_f32a_body<0>(Kf, Wb + (size_t)262144, bk, nullptr, qkout + (size_t)8388608,
                      lds, blockIdx.x*256, blockIdx.y*128, 1.0f);
  } else {
    gemm_f32a_body<0>(Qf, Wb, bq, nullptr, qkout,
                      lds, blockIdx.x*256, blockIdx.y*128, QSC_);
  }
}

// ---------------- fused attention: zinv (pass1, 16x16) + PV (pass2, 32x32 in-register P) ----------------
__global__ __launch_bounds__(512, 2)
void k_att2(const ushort* __restrict__ qp, const ushort* __restrict__ kp,
            const ushort* __restrict__ vpT, float* __restrict__ zinv,
            ushort* __restrict__ attn)
{
  __shared__ __align__(16) char kt[65536];
  __shared__ __align__(16) char vt[65536];
  __shared__ __align__(16) char qpr[32768];
  int bh = blockIdx.x;
  int b = bh >> 3, h = bh & 7;
  int t = threadIdx.x, w = t >> 6, lane = t & 63;
  int rA = lane & 15, g = lane >> 4;
  const ushort* kbase = kp + (size_t)(b*512)*512 + h*64;
  const ushort* qbase = qp + (size_t)(b*512)*512 + h*64;
  const ushort* vbase = vpT + (size_t)bh*64*512;

  // ---- issue all stages: K(8/thread), Q0(2), Q1(2), V(8) ----
#pragma unroll
  for (int i = 0; i < 8; i++) {          // K: [512][64] swizzled slot^(k&7)
    int c = i*512 + t; int row = c >> 3, sl = c & 7;
    gld16(kt + c*16, kbase + (size_t)row*512 + ((sl ^ (row & 7))*8));
  }
#define STAGE_Q(buf, qb) do { \
    _Pragma("unroll") \
    for (int i = 0; i < 2; i++) { \
      int c = i*512 + t; int row = c >> 3, sl = c & 7; \
      gld16(qpr + (buf)*16384 + c*16, \
            qbase + (size_t)((qb)*128 + row)*512 + ((sl ^ (row & 7))*8)); } } while (0)
  STAGE_Q(0, 0);
  STAGE_Q(1, 1);
#pragma unroll
  for (int i = 0; i < 8; i++) {          // V: [64][512] swizzled slot low3 ^ (d&7)
    int c = i*512 + t; int d = c >> 6, sl = c & 63;
    gld16(vt + c*16, vbase + (size_t)d*512 + ((sl ^ (d & 7))*8));
  }

  // ---- pass 1: zl[k] = 1/sum_q 2^s; wave owns k in [w*64, w*64+64) ----
  asm volatile("s_waitcnt vmcnt(10)" ::: "memory");   // K + Q0 landed (Q1,V in flight)
  __builtin_amdgcn_s_barrier();
  __builtin_amdgcn_sched_barrier(0);
  bf16x8 kf[4][2];
#pragma unroll
  for (int n = 0; n < 4; n++)
#pragma unroll
    for (int ks = 0; ks < 2; ks++) {
      int k = w*64 + n*16 + rA;
      kf[n][ks] = *(const bf16x8*)(kt + k*128 + (((ks*4 + g) ^ (k & 7))*16));
    }
  float Zacc[4] = {0.f, 0.f, 0.f, 0.f};
  for (int qb = 0; qb < 4; qb++) {
    if (qb == 1)      { asm volatile("s_waitcnt vmcnt(10)" ::: "memory"); }  // Q1 (V+Q2 out)
    else if (qb == 2) { asm volatile("s_waitcnt vmcnt(2)" ::: "memory"); }   // Q2 (Q3 out)
    else if (qb == 3) { asm volatile("s_waitcnt vmcnt(0)" ::: "memory"); }   // Q3 (+V drained)
    if (qb) { __builtin_amdgcn_s_barrier(); __builtin_amdgcn_sched_barrier(0); }
    const char* qtb = qpr + (qb & 1)*16384;
    f32x4 acc[8][4] = {};
#pragma unroll
    for (int ks = 0; ks < 2; ks++) {
      bf16x8 af[8];
#pragma unroll
      for (int m = 0; m < 8; m++) {
        int q = m*16 + rA;
        af[m] = *(const bf16x8*)(qtb + q*128 + (((ks*4 + g) ^ (q & 7))*16));
      }
      __builtin_amdgcn_s_setprio(1);
#pragma unroll
      for (int m = 0; m < 8; m++)
#pragma unroll
        for (int n = 0; n < 4; n++)
          acc[m][n] = __builtin_amdgcn_mfma_f32_16x16x32_bf16(af[m], kf[n][ks], acc[m][n], 0, 0, 0);
      __builtin_amdgcn_s_setprio(0);
    }
    if (qb < 3) __builtin_amdgcn_s_barrier();   // all waves done reading qtb
    if (qb < 2) STAGE_Q(qb & 1, qb + 2);        // restage freed buffer
#pragma unroll
    for (int m = 0; m < 8; m++)                 // exp2-sum overlaps staging DMA
#pragma unroll
      for (int n = 0; n < 4; n++) {
        float s = 0.f;
#pragma unroll
        for (int r = 0; r < 4; r++) s += ex2(acc[m][n][r]);
        Zacc[n] += s;
      }
  }
#undef STAGE_Q
#pragma unroll
  for (int n = 0; n < 4; n++) {
    float v = Zacc[n];
    v += __shfl_xor(v, 16);
    v += __shfl_xor(v, 32);
    if (lane < 16) ((float*)qpr)[w*64 + n*16 + lane] = 1.0f / v;   // zl handoff in LDS
  }
  __syncthreads();                                // zl visible; V already drained (vmcnt0 above)

  // ---- pass 2: 32x32x16, P in registers; wave owns q in [w*64, w*64+64) ----
  const int l31 = lane & 31, hi5 = lane >> 5;
  bf16x8 qf2[2][4];                               // B-op: q-col = l31, d = ksd*16 + hi5*8
#pragma unroll
  for (int qb = 0; qb < 2; qb++)
#pragma unroll
    for (int ksd = 0; ksd < 4; ksd++)
      qf2[qb][ksd] = *(const bf16x8*)(qbase + (size_t)(w*64 + qb*32 + l31)*512 + ksd*16 + hi5*8);
  const float* zl = (const float*)qpr;
  f32x16 oacc[2][2] = {};
  for (int kc = 0; kc < 16; kc++) {
    bf16x8 kf2[4];                                // A-op: k-row = l31, d = ksd*16 + hi5*8
#pragma unroll
    for (int ksd = 0; ksd < 4; ksd++) {
      int k = kc*32 + l31;
      kf2[ksd] = *(const bf16x8*)(kt + k*128 + (((ksd*2 + hi5) ^ (k & 7))*16));
    }
    bf16x8 vf2[2][2];                             // B-op: d-col = l31, k = hi5*8
#pragma unroll
    for (int db = 0; db < 2; db++)
#pragma unroll
      for (int ks = 0; ks < 2; ks++) {
        int d = db*32 + l31;
        vf2[db][ks] = *(const bf16x8*)(vt + d*1024 + (((kc*4 + ks*2 + hi5) ^ (d & 7))*16));
      }
    f32x4 zv[4];                                  // zinv[k], k uniform per (reg>>2, hi5): broadcast
#pragma unroll
    for (int j = 0; j < 4; j++)
      zv[j] = *(const f32x4*)(zl + kc*32 + j*8 + hi5*4);
#pragma unroll
    for (int qb = 0; qb < 2; qb++) {
      f32x16 s = {};
      __builtin_amdgcn_s_setprio(1);
#pragma unroll
      for (int ksd = 0; ksd < 4; ksd++)
        s = __builtin_amdgcn_mfma_f32_32x32x16_bf16(kf2[ksd], qf2[qb][ksd], s, 0, 0, 0);
      __builtin_amdgcn_s_setprio(0);
      // P[q=l31][k = (r&3) + 8*(r>>2) + 4*hi5 + kc*32] = 2^s * zinv[k]
      float e[16];
#pragma unroll
      for (int r = 0; r < 16; r++) e[r] = ex2(s[r]) * zv[r >> 2][r & 3];
      // assemble PV A-frags: cvt_pk consecutive-k pairs, permlane32_swap fills lane-halves
      uint32_t x0 = cvtpk(e[0], e[1]),   y0 = cvtpk(e[4], e[5]);
      uint32_t x1 = cvtpk(e[2], e[3]),   y1 = cvtpk(e[6], e[7]);
      uint32_t x2 = cvtpk(e[8], e[9]),   y2 = cvtpk(e[12], e[13]);
      uint32_t x3 = cvtpk(e[10], e[11]), y3 = cvtpk(e[14], e[15]);
      uint2v r0 = __builtin_amdgcn_permlane32_swap(x0, y0, false, false);
      uint2v r1 = __builtin_amdgcn_permlane32_swap(x1, y1, false, false);
      uint2v r2 = __builtin_amdgcn_permlane32_swap(x2, y2, false, false);
      uint2v r3 = __builtin_amdgcn_permlane32_swap(x3, y3, false, false);
      union { uint32_t u[4]; bf16x8 v; } p0, p1;
      p0.u[0] = r0[0]; p0.u[1] = r1[0]; p0.u[2] = r0[1]; p0.u[3] = r1[1];  // k 0..15 of chunk
      p1.u[0] = r2[0]; p1.u[1] = r3[0]; p1.u[2] = r2[1]; p1.u[3] = r3[1];  // k 16..31
      __builtin_amdgcn_s_setprio(1);
#pragma unroll
      for (int db = 0; db < 2; db++) {
        oacc[qb][db] = __builtin_amdgcn_mfma_f32_32x32x16_bf16(p0.v, vf2[db][0], oacc[qb][db], 0, 0, 0);
        oacc[qb][db] = __builtin_amdgcn_mfma_f32_32x32x16_bf16(p1.v, vf2[db][1], oacc[qb][db], 0, 0, 0);
      }
      __builtin_amdgcn_s_setprio(0);
    }
  }
#pragma unroll
  for (int qb = 0; qb < 2; qb++)
#pragma unroll
    for (int db = 0; db < 2; db++)
#pragma unroll
      for (int r = 0; r < 16; r++) {
        int q = w*64 + qb*32 + (r & 3) + 8*(r >> 2) + 4*hi5;
        int d = db*32 + l31;
        attn[(size_t)(b*512 + q)*512 + h*64 + d] = f2b(oacc[qb][db][r]);
      }
}

// ---------------- host launcher ----------------
extern "C" void kernel_launch(void* const* d_in, const int* in_sizes, int n_in,
                              void* d_out, int out_size, void* d_ws, size_t ws_size,
                              hipStream_t stream) {
  const float* Q  = (const float*)d_in[0];
  const float* K  = (const float*)d_in[1];
  const float* Wq = (const float*)d_in[2];
  const float* bq = (const float*)d_in[3];
  const float* Wk = (const float*)d_in[4];
  const float* bk = (const float*)d_in[5];
  const float* Wv = (const float*)d_in[6];
  const float* bv = (const float*)d_in[7];
  const float* Wo = (const float*)d_in[8];
  const float* bo = (const float*)d_in[9];
  const float* W1 = (const float*)d_in[10];
  const float* b1 = (const float*)d_in[11];
  const float* W2 = (const float*)d_in[12];
  const float* b2 = (const float*)d_in[13];
  float* out = (float*)d_out;

  const size_t SZ = (size_t)16384 * 512;
  ushort* attn = (ushort*)d_ws;                 // slot 0
  ushort* outb = attn + SZ;                     // slot 1
  ushort* qp   = outb + SZ;
  ushort* kp   = qp + SZ;
  ushort* vpT  = kp + SZ;                       // v-projection, transposed; later reused as h1
  ushort* Wb   = vpT + SZ;
  float*  zinv = (float*)(Wb + 6 * (size_t)262144);
  ushort* h1   = vpT;

  k_cvtw<<<dim3(1536), dim3(256), 0, stream>>>(Wq, Wk, Wv, Wo, W1, W2, Wb);
  k_gemm_qkvf<<<dim3(64, 4, 3), dim3(512), 0, stream>>>(Q, K, Wb, bq, bk, bv, qp, vpT);
  k_att2<<<dim3(256), dim3(512), 0, stream>>>(qp, kp, vpT, zinv, attn);
  k_gemm<1><<<dim3(64, 4), dim3(512), 0, stream>>>(attn, Wb + 3*(size_t)262144, bo, Q, out, outb);
  k_gemm<2><<<dim3(64, 4), dim3(512), 0, stream>>>(outb, Wb + 4*(size_t)262144, b1, nullptr, nullptr, h1);
  k_gemm<3><<<dim3(64, 4), dim3(512), 0, stream>>>(h1, Wb + 5*(size_t)262144, b2, nullptr, out, nullptr);
}